// Round 13
// baseline (385.977 us; speedup 1.0000x reference)
//
#include <hip/hip_runtime.h>
#include <math.h>

#define H 128

typedef unsigned short u16;
typedef unsigned int u32;
typedef __attribute__((ext_vector_type(4))) u32 u32x4;
typedef __attribute__((ext_vector_type(8))) __bf16 bf16x8;
typedef __attribute__((ext_vector_type(4))) float f32x4;
typedef __attribute__((ext_vector_type(16))) float f32x16;

union Frag { u32x4 u; bf16x8 b; };

// f32 pair -> packed bf16 (RNE). Native __bf16 casts: compiler emits
// v_cvt_pk_bf16_f32 (1 instr) instead of the ~7-instr software RNE path.
__device__ __forceinline__ u32 pack2(float lo, float hi) {
    union { __bf16 b[2]; u32 u; } v;
    v.b[0] = (__bf16)lo; v.b[1] = (__bf16)hi;
    return v.u;
}
__device__ __forceinline__ float bflo(u32 w) {           // low bf16 -> f32
    union { u32 i; float f; } v; v.i = w << 16; return v.f;
}
__device__ __forceinline__ float bfhi(u32 w) {           // high bf16 -> f32
    union { u32 i; float f; } v; v.i = w & 0xffff0000u; return v.f;
}
__device__ __forceinline__ float silu(float v) {
    float e = __expf(-v);
    return v * __builtin_amdgcn_rcpf(1.0f + e);
}
__device__ __forceinline__ bf16x8 f8frag(float4 lo, float4 hi) {
    Frag f;
    f.u = (u32x4){pack2(lo.x, lo.y), pack2(lo.z, lo.w),
                  pack2(hi.x, hi.y), pack2(hi.z, hi.w)};
    return f.b;
}
__device__ __forceinline__ f32x16 mfma(bf16x8 a, bf16x8 b, f32x16 c) {
    return __builtin_amdgcn_mfma_f32_32x32x16_bf16(a, b, c, 0, 0, 0);
}
__device__ __forceinline__ f32x4 mfma16(bf16x8 a, bf16x8 b, f32x4 c) {
    return __builtin_amdgcn_mfma_f32_16x16x32_bf16(a, b, c, 0, 0, 0);
}
// VALU-pipe cross-lane add within 16-lane rows: v += row_ror(v, N)
#define DPP_RADD(v, ctrl) \
    (v) += __int_as_float(__builtin_amdgcn_update_dpp(0, __float_as_int(v), (ctrl), 0xf, 0xf, 1))

// ---------------------------------------------------------------------------
// ws frag region (u32 units):
//   mw1s @ 0      : 4ct x 17kb x 64lane x 4   (msg w1^T 32x32 frags; kb16 = dist+b1)
//   mw2s @ 17408  : 4ct x  9kb x 64lane x 4   (msg w2^T 32x32 frags; kb8 = b2)
//   uw1s @ 26624  : 4ct x 17kb x 64lane x 4   (upd w1^T 32x32 frags; kb16 = b1)
//   uw2s @ 44032  : 4ct x  9kb x 64lane x 4   (upd w2^T 32x32 frags; kb8 = b2)
//   m16s @ 53248  : 5kb x 8mt x 64lane x 4    (msg w2 16x16 A-frags)
//   wdp  @ 63488  : 64 u32                    (dist-row weights packed bf16)
// ---------------------------------------------------------------------------
__global__ void prep_kernel(const float* __restrict__ mw1, const float* __restrict__ mb1,
                            const float* __restrict__ mw2, const float* __restrict__ mb2,
                            const float* __restrict__ uw1, const float* __restrict__ ub1,
                            const float* __restrict__ uw2, const float* __restrict__ ub2,
                            u32* __restrict__ ws) {
    int t = blockIdx.x * blockDim.x + threadIdx.x;
    if (t >= 15936) return;
    if (t >= 15872) {
        // ---- dist-row weights, packed bf16 ----
        int i = t - 15872;                    // [0, 64)
        ws[63488 + i] = pack2(mw1[256 * H + 2 * i], mw1[256 * H + 2 * i + 1]);
        return;
    }
    if (t >= 13312) {
        // ---- 16x16 A-frags of msg w2 ----
        int slot = t - 13312;                 // (kb*8 + mt)*64 + lane
        int lane = slot & 63, fb = slot >> 6;
        int kb = fb >> 3, mt = fb & 7;
        int m = mt * 16 + (lane & 15);
        int quad = lane >> 4;
        u32 out[4];
        #pragma unroll
        for (int p = 0; p < 4; ++p) {
            float v[2];
            #pragma unroll
            for (int h = 0; h < 2; ++h) {
                int k = kb * 32 + quad * 8 + p * 2 + h;
                float val = 0.0f;
                if (k < 128)       val = mw2[(size_t)k * H + m];
                else if (k == 128) val = mb2[m];
                v[h] = val;
            }
            out[p] = pack2(v[0], v[1]);
        }
        u32* dst = ws + 53248 + (size_t)slot * 4;
        dst[0] = out[0]; dst[1] = out[1]; dst[2] = out[2]; dst[3] = out[3];
        return;
    }
    const float *W, *s0, *s1;
    int nK, slot, base;
    if (t < 4352)       { W = mw1; s0 = mw1 + 256 * H; s1 = mb1; nK = 256; slot = t;         base = 0;     }
    else if (t < 6656)  { W = mw2; s0 = mb2; s1 = nullptr;       nK = 128; slot = t - 4352;  base = 17408; }
    else if (t < 11008) { W = uw1; s0 = ub1; s1 = nullptr;       nK = 256; slot = t - 6656;  base = 26624; }
    else                { W = uw2; s0 = ub2; s1 = nullptr;       nK = 128; slot = t - 11008; base = 44032; }
    int lane = slot & 63, fb = slot >> 6;
    int ct, kb;
    if (nK == 256) { ct = fb / 17; kb = fb % 17; }
    else           { ct = fb / 9;  kb = fb % 9;  }
    int m = ct * 32 + (lane & 31);
    int q = lane >> 5;
    u32 out[4];
    #pragma unroll
    for (int p = 0; p < 4; ++p) {
        float v[2];
        #pragma unroll
        for (int h = 0; h < 2; ++h) {
            int k = kb * 16 + q * 8 + p * 2 + h;
            float val = 0.0f;
            if (k < nK)            val = W[(size_t)k * H + m];
            else if (k == nK)      val = s0 ? s0[m] : 0.0f;
            else if (k == nK + 1)  val = s1 ? s1[m] : 0.0f;
            v[h] = val;
        }
        out[p] = pack2(v[0], v[1]);
    }
    u32* dst = ws + base + (size_t)slot * 4;
    dst[0] = out[0]; dst[1] = out[1]; dst[2] = out[2]; dst[3] = out[3];
}

// ---------------------------------------------------------------------------
// front_kernel (R9, parallel fusion — proven −25..40 us vs serial):
//   blocks [0, PQB)        : P GEMM  (x @ W1[0:128], packed bf16 out)
//   blocks [PQB, 2*PQB)    : Q GEMM  (x @ W1[128:256] + b1, packed bf16 out)
//   blocks [2*PQB, +BKB)   : bucket_fill (grid-stride over E edges)
// ---------------------------------------------------------------------------
__global__ __launch_bounds__(256, 2) void front_kernel(
    const float* __restrict__ x, const u32* __restrict__ mw1s,
    u32* __restrict__ Pb, u32* __restrict__ Qb,
    const float* __restrict__ pos, const int* __restrict__ ei,
    int* __restrict__ deg, int2* __restrict__ bucket,
    int N, int E, int nIter, int PQB, int BKB)
{
    const int b = blockIdx.x;
    if (b < 2 * PQB) {
        // ---- P or Q GEMM (R5 pq_gemm body, 32 nodes/wave) ----
        const int isQ = (b >= PQB);
        const int bb = isQ ? (b - PQB) : b;
        const int kbBase = isQ ? 8 : 0;
        u32* outb = isQ ? Qb : Pb;

        const int lane = threadIdx.x & 63;
        const int q = lane >> 5, el = lane & 31;
        const int gw  = bb * 4 + (threadIdx.x >> 6);
        const int gws = PQB * 4;

        for (int it = gw; it < nIter; it += gws) {
            const int nA = it * 32 + el;
            const int ncA = (nA < N) ? nA : (N - 1);
            const float* xA = x + (size_t)ncA * H;

            f32x16 acc[4];
            #pragma unroll
            for (int ct = 0; ct < 4; ++ct) acc[ct] = (f32x16)0.0f;

            #pragma unroll
            for (int kb = 0; kb < 8; ++kb) {
                const int f = kb * 16 + q * 8;
                bf16x8 bA = f8frag(*(const float4*)(xA + f), *(const float4*)(xA + f + 4));
                #pragma unroll
                for (int ct = 0; ct < 4; ++ct) {
                    Frag a; a.u = *(const u32x4*)&mw1s[((size_t)(ct * 17 + kbBase + kb) * 64 + lane) * 4];
                    acc[ct] = mfma(a.b, bA, acc[ct]);
                }
            }
            if (isQ) {   // pad kb16: k=256 -> 0 (skip dist row), k=257 -> 1.0 (b1)
                Frag bp; bp.u = (u32x4){0, 0, 0, 0};
                if (q == 0) bp.u.x = pack2(0.0f, 1.0f);
                #pragma unroll
                for (int ct = 0; ct < 4; ++ct) {
                    Frag a; a.u = *(const u32x4*)&mw1s[((size_t)(ct * 17 + 16) * 64 + lane) * 4];
                    acc[ct] = mfma(a.b, bp.b, acc[ct]);
                }
            }
            if (nA < N) {
                u32* prow = outb + (size_t)nA * 64;
                #pragma unroll
                for (int ct = 0; ct < 4; ++ct)
                    #pragma unroll
                    for (int g = 0; g < 4; ++g) {
                        u32 a = pack2(acc[ct][4*g + 0], acc[ct][4*g + 1]);
                        u32 bb2 = pack2(acc[ct][4*g + 2], acc[ct][4*g + 3]);
                        *(uint2*)(prow + ct * 16 + 4 * g + 2 * q) = make_uint2(a, bb2);
                    }
            }
        }
    } else {
        // ---- bucket_fill: grid-stride over edges ----
        const int bb = b - 2 * PQB;
        for (int e = bb * 256 + (int)threadIdx.x; e < E; e += BKB * 256) {
            const int s = ei[e];
            const int r = ei[E + e];
            const float dx = pos[s*3]   - pos[r*3];
            const float dy = pos[s*3+1] - pos[r*3+1];
            const float dz = pos[s*3+2] - pos[r*3+2];
            const float dist = sqrtf(dx*dx + dy*dy + dz*dz);
            int slot = atomicAdd(&deg[r], 1);
            if (slot < 64) bucket[(size_t)r * 64 + slot] = make_int2(s, __float_as_int(dist));
        }
    }
}

// ---------------------------------------------------------------------------
// aggregate (16x16): one wave per node n in [n0,n1). R9-proven config:
// (256,3)/768 = exactly 3/CU, VGPR 72, WRITE 25 MB, ~53 us per third.
// Closed levers: occupancy (R3/R8 spill wall), prefetch (R6 null),
// VALU-count (R10 null/regress).
// R13: THREE-way range split (diagnostic): drops per-dispatch max to ~53 us
// so node_mfma (post-scratch-fix, unverified) and front_kernel (never
// profiled) surface in top-5 with counters. ~5-10 us temporary cost.
// ---------------------------------------------------------------------------
__global__ __launch_bounds__(256, 3) void aggregate_kernel(
    const u32* __restrict__ Pbf, const u32* __restrict__ Qbf,
    const u32* __restrict__ wdp, const u32* __restrict__ ws16,
    const float* __restrict__ mb2,
    const int* __restrict__ deg, const int2* __restrict__ bucket,
    float* __restrict__ out, int n0, int n1)
{
    __shared__ u32x4 af[2048];                        // 32 KiB: w2 16x16 A-frags
    __shared__ float b2s[128];                        // b2 fp32 (C-init source)
    __shared__ u32x4 wds[16];                         // dist-row weights (packed bf16)
    for (int i = threadIdx.x; i < 2048; i += 256) af[i] = ((const u32x4*)ws16)[i];
    for (int i = threadIdx.x; i < 128; i += 256) b2s[i] = mb2[i];
    if (threadIdx.x < 16) wds[threadIdx.x] = ((const u32x4*)wdp)[threadIdx.x];
    __syncthreads();

    const int lane = threadIdx.x & 63;
    const int quad = lane >> 4, col = lane & 15;

    const int gw  = blockIdx.x * 4 + (threadIdx.x >> 6);
    const int gws = gridDim.x * 4;

    for (int n = n0 + gw; n < n1; n += gws) {
        int dn = deg[n]; dn = (dn > 64) ? 64 : dn;
        const int nt = (dn + 15) >> 4;
        const u32x4* Qrow = (const u32x4*)(Qbf + (size_t)n * 64);

        f32x4 sum[8];
        #pragma unroll
        for (int mt = 0; mt < 8; ++mt) sum[mt] = (f32x4){0.f, 0.f, 0.f, 0.f};

        for (int t = 0; t < nt; ++t) {
            const int eIdx = t * 16 + col;
            const bool valid = eIdx < dn;
            const int eC = valid ? eIdx : (dn - 1);
            const int2 rec = bucket[(size_t)n * 64 + eC];
            const u32x4* Prow = (const u32x4*)(Pbf + (size_t)rec.x * 64);
            const float dist = __int_as_float(rec.y);

            f32x4 acc[8];                             // C-init = b2 (per-row)
            #pragma unroll
            for (int mt = 0; mt < 8; ++mt)
                acc[mt] = *(const f32x4*)&b2s[mt * 16 + quad * 4];

            #pragma unroll 2
            for (int kb = 0; kb < 4; ++kb) {
                const u32x4 pc = Prow[kb * 4 + quad];
                const u32x4 qc = Qrow[kb * 4 + quad];
                const u32x4 wc = wds[kb * 4 + quad];
                const float v0 = silu(bflo(pc.x) + bflo(qc.x) + dist * bflo(wc.x));
                const float v1 = silu(bfhi(pc.x) + bfhi(qc.x) + dist * bfhi(wc.x));
                const float v2 = silu(bflo(pc.y) + bflo(qc.y) + dist * bflo(wc.y));
                const float v3 = silu(bfhi(pc.y) + bfhi(qc.y) + dist * bfhi(wc.y));
                const float v4 = silu(bflo(pc.z) + bflo(qc.z) + dist * bflo(wc.z));
                const float v5 = silu(bfhi(pc.z) + bfhi(qc.z) + dist * bfhi(wc.z));
                const float v6 = silu(bflo(pc.w) + bflo(qc.w) + dist * bflo(wc.w));
                const float v7 = silu(bfhi(pc.w) + bfhi(qc.w) + dist * bfhi(wc.w));
                Frag bf;
                bf.u = (u32x4){pack2(v0, v1), pack2(v2, v3), pack2(v4, v5), pack2(v6, v7)};
                if (!valid) bf.u = (u32x4){0, 0, 0, 0};
                #pragma unroll
                for (int mt = 0; mt < 8; ++mt) {
                    Frag a; a.u = af[(kb * 8 + mt) * 64 + lane];
                    acc[mt] = mfma16(a.b, bf.b, acc[mt]);
                }
            }
            // lane's D values all belong to its own column (= its own edge):
            // invalid columns (D == b2) are masked here.
            #pragma unroll
            for (int mt = 0; mt < 8; ++mt) {
                sum[mt][0] += valid ? silu(acc[mt][0]) : 0.0f;
                sum[mt][1] += valid ? silu(acc[mt][1]) : 0.0f;
                sum[mt][2] += valid ? silu(acc[mt][2]) : 0.0f;
                sum[mt][3] += valid ? silu(acc[mt][3]) : 0.0f;
            }
        }

        // reduce over the 16 column-lanes: DPP row rotations, pure VALU
        #pragma unroll
        for (int mt = 0; mt < 8; ++mt)
            #pragma unroll
            for (int r = 0; r < 4; ++r) {
                float v = sum[mt][r];
                DPP_RADD(v, 0x128);   // row_ror:8
                DPP_RADD(v, 0x124);   // row_ror:4
                DPP_RADD(v, 0x122);   // row_ror:2
                DPP_RADD(v, 0x121);   // row_ror:1
                sum[mt][r] = v;
            }
        if (col == 0) {               // lanes 0,16,32,48: rows quad*4..+3 per mt
            float* orow = out + (size_t)n * H;
            #pragma unroll
            for (int mt = 0; mt < 8; ++mt) {
                float4 v = { sum[mt][0], sum[mt][1], sum[mt][2], sum[mt][3] };
                *(float4*)(orow + mt * 16 + quad * 4) = v;
            }
        }
    }
}

// ---------------------------------------------------------------------------
// FALLBACK (ws too small): round-3 edge kernel with fp32 atomics.
// ---------------------------------------------------------------------------
__global__ __launch_bounds__(256, 2) void edge_mfma(
    const float* __restrict__ x, const float* __restrict__ pos,
    const int* __restrict__ ei, const u32* __restrict__ ws,
    float* __restrict__ aggr, int E, int nIter)
{
    __shared__ u32 lds[16384];
    {
        const u32x4* src = (const u32x4*)ws;
        u32x4* dst = (u32x4*)lds;
        for (int i = threadIdx.x; i < 4096; i += 256) {
            int ln = i & 63, fb = i >> 6, ct = fb >> 4, kb = fb & 15;
            dst[i] = src[(ct * 17 + kb) * 64 + ln];
        }
    }
    __syncthreads();
    const u32* wsl1 = ws;
    const u32* wsl2 = ws + 17408;

    const int lane = threadIdx.x & 63;
    const int q = lane >> 5, el = lane & 31;
    const int gw  = blockIdx.x * 4 + (threadIdx.x >> 6);
    const int gws = gridDim.x * 4;

    for (int it = gw; it < nIter; it += gws) {
        const int e0 = it * 64;
        const int sA = ei[e0 + el],      rA = ei[E + e0 + el];
        const int sB = ei[e0 + 32 + el], rB = ei[E + e0 + 32 + el];
        float dA, dB;
        {
            float ax = pos[sA*3] - pos[rA*3], ay = pos[sA*3+1] - pos[rA*3+1], az = pos[sA*3+2] - pos[rA*3+2];
            dA = sqrtf(ax*ax + ay*ay + az*az);
            float bx = pos[sB*3] - pos[rB*3], by = pos[sB*3+1] - pos[rB*3+1], bz = pos[sB*3+2] - pos[rB*3+2];
            dB = sqrtf(bx*bx + by*by + bz*bz);
        }
        const float* xsA = x + (size_t)sA * H; const float* xrA = x + (size_t)rA * H;
        const float* xsB = x + (size_t)sB * H; const float* xrB = x + (size_t)rB * H;

        f32x16 acc[2][4];
        #pragma unroll
        for (int s = 0; s < 2; ++s)
            #pragma unroll
            for (int ct = 0; ct < 4; ++ct) acc[s][ct] = (f32x16)0.0f;

        #pragma unroll
        for (int kb = 0; kb < 16; ++kb) {
            const int f = kb * 16 + q * 8;
            const float* pA = (f < H) ? (xsA + f) : (xrA + f - H);
            const float* pB = (f < H) ? (xsB + f) : (xrB + f - H);
            bf16x8 bA = f8frag(*(const float4*)pA, *(const float4*)(pA + 4));
            bf16x8 bB = f8frag(*(const float4*)pB, *(const float4*)(pB + 4));
            #pragma unroll
            for (int ct = 0; ct < 4; ++ct) {
                Frag a; a.u = *(const u32x4*)&lds[((ct * 16 + kb) * 64 + lane) * 4];
                acc[0][ct] = mfma(a.b, bA, acc[0][ct]);
                acc[1][ct] = mfma(a.b, bB, acc[1][ct]);
            }
        }
        {
            Frag bA, bB;
            bA.u = (u32x4){0,0,0,0}; bB.u = (u32x4){0,0,0,0};
            if (q == 0) { bA.u.x = pack2(dA, 1.0f); bB.u.x = pack2(dB, 1.0f); }
            #pragma unroll
            for (int ct = 0; ct < 4; ++ct) {
                Frag a; a.u = *(const u32x4*)&wsl1[((size_t)(ct * 17 + 16) * 64 + lane) * 4];
                acc[0][ct] = mfma(a.b, bA.b, acc[0][ct]);
                acc[1][ct] = mfma(a.b, bB.b, acc[1][ct]);
            }
        }

        #pragma unroll
        for (int s = 0; s < 2; ++s) {
            const int ridx = s ? rB : rA;
            u32 hp[16][2];
            #pragma unroll
            for (int ct = 0; ct < 4; ++ct)
                #pragma unroll
                for (int g = 0; g < 4; ++g) {
                    hp[ct * 4 + g][0] = pack2(silu(acc[s][ct][4*g + 0]), silu(acc[s][ct][4*g + 1]));
                    hp[ct * 4 + g][1] = pack2(silu(acc[s][ct][4*g + 2]), silu(acc[s][ct][4*g + 3]));
                }

            f32x16 acc2[4];
            #pragma unroll
            for (int ct = 0; ct < 4; ++ct) acc2[ct] = (f32x16)0.0f;

            #pragma unroll
            for (int kb2 = 0; kb2 < 8; ++kb2) {
                const u32 e0v = hp[2 * kb2][0],     e1v = hp[2 * kb2][1];
                const u32 o0v = hp[2 * kb2 + 1][0], o1v = hp[2 * kb2 + 1][1];
                const u32 w0  = q ? o0v : e0v;
                const u32 w1v = q ? o1v : e1v;
                const u32 sv0 = q ? e0v : o0v;
                const u32 sv1 = q ? e1v : o1v;
                u32 r0 = (u32)__shfl((int)sv0, lane ^ 32);
                u32 r1 = (u32)__shfl((int)sv1, lane ^ 32);
                Frag bf;
                if (q == 0) bf.u = (u32x4){w0, w1v, r0, r1};
                else        bf.u = (u32x4){r0, r1, w0, w1v};
                #pragma unroll
                for (int ct2 = 0; ct2 < 4; ++ct2) {
                    Frag a; a.u = *(const u32x4*)&wsl2[((size_t)(ct2 * 9 + kb2) * 64 + lane) * 4];
                    acc2[ct2] = mfma(a.b, bf.b, acc2[ct2]);
                }
            }
            {
                Frag bf; bf.u = (u32x4){0,0,0,0};
                if (q == 0) bf.u.x = 0x00003F80u;
                #pragma unroll
                for (int ct2 = 0; ct2 < 4; ++ct2) {
                    Frag a; a.u = *(const u32x4*)&wsl2[((size_t)(ct2 * 9 + 8) * 64 + lane) * 4];
                    acc2[ct2] = mfma(a.b, bf.b, acc2[ct2]);
                }
            }
            float* arow = aggr + (size_t)ridx * H;
            #pragma unroll
            for (int ct2 = 0; ct2 < 4; ++ct2)
                #pragma unroll
                for (int r = 0; r < 16; ++r) {
                    int m = ct2 * 32 + (r & 3) + 8 * (r >> 2) + 4 * q;
                    atomicAdd(arow + m, silu(acc2[ct2][r]));
                }
        }
    }
}

// ---------------------------------------------------------------------------
// Node update MLP: update = silu([x, aggr] @ uw1 + ub1) @ uw2 + ub2
// buf == d_out: aggr rows on entry, overwritten with the final update.
// R12 FIX (rule #20): hp literal-indexed (flat [16][2], q?: selects) — total
// improved 381->369.7 but node fix Δ (~11 us) < predicted (40-60). R13:
// verify with counters (WRITE ~26 MB = fix took; ~146 MB = scratch remains).
// ---------------------------------------------------------------------------
__global__ __launch_bounds__(256, 2) void node_mfma(
    const float* __restrict__ x, float* __restrict__ buf,
    const u32* __restrict__ ws, int N, int nIter)
{
    __shared__ u32 lds[16384];
    const u32* wsl1 = ws + 26624;
    const u32* wsl2 = ws + 44032;
    {
        const u32x4* src = (const u32x4*)wsl1;
        u32x4* dst = (u32x4*)lds;
        for (int i = threadIdx.x; i < 4096; i += 256) {
            int ln = i & 63, fb = i >> 6, ct = fb >> 4, kb = fb & 15;
            dst[i] = src[(ct * 17 + kb) * 64 + ln];
        }
    }
    __syncthreads();

    const int lane = threadIdx.x & 63;
    const int q = lane >> 5, el = lane & 31;
    const int gw  = blockIdx.x * 4 + (threadIdx.x >> 6);
    const int gws = gridDim.x * 4;

    for (int it = gw; it < nIter; it += gws) {
        const int nA = it * 32 + el;
        const int ncA = (nA < N) ? nA : (N - 1);
        const float* xA = x + (size_t)ncA * H;
        const float* gA = buf + (size_t)ncA * H;

        f32x16 acc[4];
        #pragma unroll
        for (int ct = 0; ct < 4; ++ct) acc[ct] = (f32x16)0.0f;

        #pragma unroll
        for (int kb = 0; kb < 16; ++kb) {
            const int f = kb * 16 + q * 8;
            const float* pA = (f < H) ? (xA + f) : (gA + f - H);
            bf16x8 bA = f8frag(*(const float4*)pA, *(const float4*)(pA + 4));
            #pragma unroll
            for (int ct = 0; ct < 4; ++ct) {
                Frag a; a.u = *(const u32x4*)&lds[((ct * 16 + kb) * 64 + lane) * 4];
                acc[ct] = mfma(a.b, bA, acc[ct]);
            }
        }
        {
            Frag bp; bp.u = (u32x4){0,0,0,0};
            if (q == 0) bp.u.x = 0x00003F80u;
            #pragma unroll
            for (int ct = 0; ct < 4; ++ct) {
                Frag a; a.u = *(const u32x4*)&wsl1[((size_t)(ct * 17 + 16) * 64 + lane) * 4];
                acc[ct] = mfma(a.b, bp.b, acc[ct]);
            }
        }

        // flat hp: hp[i] for output-block i = ct*4+g; ALL indices literal.
        u32 hp[16][2];
        #pragma unroll
        for (int ct = 0; ct < 4; ++ct)
            #pragma unroll
            for (int g = 0; g < 4; ++g) {
                hp[ct * 4 + g][0] = pack2(silu(acc[ct][4*g + 0]), silu(acc[ct][4*g + 1]));
                hp[ct * 4 + g][1] = pack2(silu(acc[ct][4*g + 2]), silu(acc[ct][4*g + 3]));
            }

        f32x16 acc2[4];
        #pragma unroll
        for (int ct = 0; ct < 4; ++ct) acc2[ct] = (f32x16)0.0f;

        #pragma unroll
        for (int kb2 = 0; kb2 < 8; ++kb2) {
            // om = 2*kb2 + q, op = 2*kb2 + 1 - q: select even/odd pair by q.
            const u32 e0v = hp[2 * kb2][0],     e1v = hp[2 * kb2][1];
            const u32 o0v = hp[2 * kb2 + 1][0], o1v = hp[2 * kb2 + 1][1];
            const u32 w0  = q ? o0v : e0v;      // hp[om]
            const u32 w1v = q ? o1v : e1v;
            const u32 sv0 = q ? e0v : o0v;      // hp[op]
            const u32 sv1 = q ? e1v : o1v;
            u32 r0 = (u32)__shfl((int)sv0, lane ^ 32);
            u32 r1 = (u32)__shfl((int)sv1, lane ^ 32);
            Frag bf;
            if (q == 0) bf.u = (u32x4){w0, w1v, r0, r1};
            else        bf.u = (u32x4){r0, r1, w0, w1v};
            #pragma unroll
            for (int ct2 = 0; ct2 < 4; ++ct2) {
                Frag a; a.u = *(const u32x4*)&wsl2[((size_t)(ct2 * 9 + kb2) * 64 + lane) * 4];
                acc2[ct2] = mfma(a.b, bf.b, acc2[ct2]);
            }
        }
        {
            Frag bf; bf.u = (u32x4){0,0,0,0};
            if (q == 0) bf.u.x = 0x00003F80u;
            #pragma unroll
            for (int ct2 = 0; ct2 < 4; ++ct2) {
                Frag a; a.u = *(const u32x4*)&wsl2[((size_t)(ct2 * 9 + 8) * 64 + lane) * 4];
                acc2[ct2] = mfma(a.b, bf.b, acc2[ct2]);
            }
        }
        if (nA < N) {
            float* orow = buf + (size_t)nA * H;
            #pragma unroll
            for (int ct2 = 0; ct2 < 4; ++ct2)
                #pragma unroll
                for (int g = 0; g < 4; ++g) {
                    float4 v = { acc2[ct2][4*g + 0], acc2[ct2][4*g + 1],
                                 acc2[ct2][4*g + 2], acc2[ct2][4*g + 3] };
                    *(float4*)(orow + ct2 * 32 + 8 * g + 4 * q) = v;
                }
        }
    }
}

extern "C" void kernel_launch(void* const* d_in, const int* in_sizes, int n_in,
                              void* d_out, int out_size, void* d_ws, size_t ws_size,
                              hipStream_t stream) {
    const float* x    = (const float*)d_in[0];
    const float* pos  = (const float*)d_in[1];
    const int*   ei   = (const int*)d_in[2];
    const float* mw1  = (const float*)d_in[3];
    const float* mb1  = (const float*)d_in[4];
    const float* mw2  = (const float*)d_in[5];
    const float* mb2  = (const float*)d_in[6];
    const float* uw1  = (const float*)d_in[7];
    const float* ub1  = (const float*)d_in[8];
    const float* uw2  = (const float*)d_in[9];
    const float* ub2  = (const float*)d_in[10];

    const int N = in_sizes[0] / H;
    const int E = in_sizes[2] / 2;

    // ws layout (u32 units) — R9 layout
    const size_t FRAGS = 53248 + 10240 + 64;     // 32x32 frags + 16x16 frags + wdp
    const size_t PO = FRAGS;                     // P: N*64 u32 (packed bf16 rows)
    const size_t QO = PO + (size_t)N * 64;       // Q: N*64 u32 (packed bf16 rows)
    const size_t DG = QO + (size_t)N * 64;       // deg: N int
    const size_t BK = DG + (size_t)N;            // bucket: N*64 int2
    const size_t ENDu = BK + (size_t)N * 128;
    const size_t need_bytes = ENDu * 4;

    u32* ws = (u32*)d_ws;
    prep_kernel<<<63, 256, 0, stream>>>(mw1, mb1, mw2, mb2, uw1, ub1, uw2, ub2, ws);

    float* buf = (float*)d_out;
    const int nIter32 = (N + 31) / 32;           // 32 nodes per wave

    if (ws_size >= need_bytes) {
        // ---- gather path: no fp32 atomics ----
        u32*   Pb   = ws + PO;
        u32*   Qb   = ws + QO;
        int*   deg  = (int*)(ws + DG);
        int2*  bkt  = (int2*)(ws + BK);

        hipMemsetAsync(deg, 0, (size_t)N * sizeof(int), stream);

        // P-GEMM || Q-GEMM || bucket_fill, one launch (parallel fusion, R9)
        const int PQB = 392;                      // 392*4 = 1568 waves >= 1563 iters
        const int BKB = 640;                      // grid-stride, ~3.9 edges/thread
        front_kernel<<<2 * PQB + BKB, 256, 0, stream>>>(
            x, ws, Pb, Qb, pos, ei, deg, bkt, N, E, nIter32, PQB, BKB);

        // R13 diagnostic: three third-range dispatches (~53 us each) to
        // surface node_mfma (fix verification) and front_kernel counters.
        const int third = N / 3;
        aggregate_kernel<<<768, 256, 0, stream>>>(Pb, Qb, ws + 63488, ws + 53248,
                                                  mb2, deg, bkt, buf, 0, third);
        aggregate_kernel<<<768, 256, 0, stream>>>(Pb, Qb, ws + 63488, ws + 53248,
                                                  mb2, deg, bkt, buf, third, 2 * third);
        aggregate_kernel<<<768, 256, 0, stream>>>(Pb, Qb, ws + 63488, ws + 53248,
                                                  mb2, deg, bkt, buf, 2 * third, N);
        node_mfma<<<512, 256, 0, stream>>>(x, buf, ws, N, nIter32);
    } else {
        // ---- fallback: round-3 atomic scatter path ----
        hipMemsetAsync(buf, 0, (size_t)N * H * sizeof(float), stream);
        edge_mfma<<<512, 256, 0, stream>>>(x, pos, ei, ws, buf, E, E / 64);
        node_mfma<<<512, 256, 0, stream>>>(x, buf, ws, N, nIter32);
    }
}

// Round 14
// 338.420 us; speedup vs baseline: 1.1405x; 1.1405x over previous
//
#include <hip/hip_runtime.h>
#include <math.h>

#define H 128

typedef unsigned short u16;
typedef unsigned int u32;
typedef __attribute__((ext_vector_type(4))) u32 u32x4;
typedef __attribute__((ext_vector_type(8))) __bf16 bf16x8;
typedef __attribute__((ext_vector_type(4))) float f32x4;
typedef __attribute__((ext_vector_type(16))) float f32x16;

union Frag { u32x4 u; bf16x8 b; };

// f32 pair -> packed bf16 (RNE). Native __bf16 casts: compiler emits
// v_cvt_pk_bf16_f32 (1 instr) instead of the ~7-instr software RNE path.
__device__ __forceinline__ u32 pack2(float lo, float hi) {
    union { __bf16 b[2]; u32 u; } v;
    v.b[0] = (__bf16)lo; v.b[1] = (__bf16)hi;
    return v.u;
}
__device__ __forceinline__ float bflo(u32 w) {           // low bf16 -> f32
    union { u32 i; float f; } v; v.i = w << 16; return v.f;
}
__device__ __forceinline__ float bfhi(u32 w) {           // high bf16 -> f32
    union { u32 i; float f; } v; v.i = w & 0xffff0000u; return v.f;
}
__device__ __forceinline__ float silu(float v) {
    float e = __expf(-v);
    return v * __builtin_amdgcn_rcpf(1.0f + e);
}
__device__ __forceinline__ bf16x8 f8frag(float4 lo, float4 hi) {
    Frag f;
    f.u = (u32x4){pack2(lo.x, lo.y), pack2(lo.z, lo.w),
                  pack2(hi.x, hi.y), pack2(hi.z, hi.w)};
    return f.b;
}
__device__ __forceinline__ f32x16 mfma(bf16x8 a, bf16x8 b, f32x16 c) {
    return __builtin_amdgcn_mfma_f32_32x32x16_bf16(a, b, c, 0, 0, 0);
}
__device__ __forceinline__ f32x4 mfma16(bf16x8 a, bf16x8 b, f32x4 c) {
    return __builtin_amdgcn_mfma_f32_16x16x32_bf16(a, b, c, 0, 0, 0);
}
// VALU-pipe cross-lane add within 16-lane rows: v += row_ror(v, N)
#define DPP_RADD(v, ctrl) \
    (v) += __int_as_float(__builtin_amdgcn_update_dpp(0, __float_as_int(v), (ctrl), 0xf, 0xf, 1))

// ---------------------------------------------------------------------------
// ws frag region (u32 units):
//   mw1s @ 0      : 4ct x 17kb x 64lane x 4   (msg w1^T 32x32 frags; kb16 = dist+b1)
//   mw2s @ 17408  : 4ct x  9kb x 64lane x 4   (msg w2^T 32x32 frags; kb8 = b2)
//   uw1s @ 26624  : 4ct x 17kb x 64lane x 4   (upd w1^T 32x32 frags; kb16 = b1)
//   uw2s @ 44032  : 4ct x  9kb x 64lane x 4   (upd w2^T 32x32 frags; kb8 = b2)
//   m16s @ 53248  : 5kb x 8mt x 64lane x 4    (msg w2 16x16 A-frags)
//   wdp  @ 63488  : 64 u32                    (dist-row weights packed bf16)
// ---------------------------------------------------------------------------
__global__ void prep_kernel(const float* __restrict__ mw1, const float* __restrict__ mb1,
                            const float* __restrict__ mw2, const float* __restrict__ mb2,
                            const float* __restrict__ uw1, const float* __restrict__ ub1,
                            const float* __restrict__ uw2, const float* __restrict__ ub2,
                            u32* __restrict__ ws) {
    int t = blockIdx.x * blockDim.x + threadIdx.x;
    if (t >= 15936) return;
    if (t >= 15872) {
        // ---- dist-row weights, packed bf16 ----
        int i = t - 15872;                    // [0, 64)
        ws[63488 + i] = pack2(mw1[256 * H + 2 * i], mw1[256 * H + 2 * i + 1]);
        return;
    }
    if (t >= 13312) {
        // ---- 16x16 A-frags of msg w2 ----
        int slot = t - 13312;                 // (kb*8 + mt)*64 + lane
        int lane = slot & 63, fb = slot >> 6;
        int kb = fb >> 3, mt = fb & 7;
        int m = mt * 16 + (lane & 15);
        int quad = lane >> 4;
        u32 out[4];
        #pragma unroll
        for (int p = 0; p < 4; ++p) {
            float v[2];
            #pragma unroll
            for (int h = 0; h < 2; ++h) {
                int k = kb * 32 + quad * 8 + p * 2 + h;
                float val = 0.0f;
                if (k < 128)       val = mw2[(size_t)k * H + m];
                else if (k == 128) val = mb2[m];
                v[h] = val;
            }
            out[p] = pack2(v[0], v[1]);
        }
        u32* dst = ws + 53248 + (size_t)slot * 4;
        dst[0] = out[0]; dst[1] = out[1]; dst[2] = out[2]; dst[3] = out[3];
        return;
    }
    const float *W, *s0, *s1;
    int nK, slot, base;
    if (t < 4352)       { W = mw1; s0 = mw1 + 256 * H; s1 = mb1; nK = 256; slot = t;         base = 0;     }
    else if (t < 6656)  { W = mw2; s0 = mb2; s1 = nullptr;       nK = 128; slot = t - 4352;  base = 17408; }
    else if (t < 11008) { W = uw1; s0 = ub1; s1 = nullptr;       nK = 256; slot = t - 6656;  base = 26624; }
    else                { W = uw2; s0 = ub2; s1 = nullptr;       nK = 128; slot = t - 11008; base = 44032; }
    int lane = slot & 63, fb = slot >> 6;
    int ct, kb;
    if (nK == 256) { ct = fb / 17; kb = fb % 17; }
    else           { ct = fb / 9;  kb = fb % 9;  }
    int m = ct * 32 + (lane & 31);
    int q = lane >> 5;
    u32 out[4];
    #pragma unroll
    for (int p = 0; p < 4; ++p) {
        float v[2];
        #pragma unroll
        for (int h = 0; h < 2; ++h) {
            int k = kb * 16 + q * 8 + p * 2 + h;
            float val = 0.0f;
            if (k < nK)            val = W[(size_t)k * H + m];
            else if (k == nK)      val = s0 ? s0[m] : 0.0f;
            else if (k == nK + 1)  val = s1 ? s1[m] : 0.0f;
            v[h] = val;
        }
        out[p] = pack2(v[0], v[1]);
    }
    u32* dst = ws + base + (size_t)slot * 4;
    dst[0] = out[0]; dst[1] = out[1]; dst[2] = out[2]; dst[3] = out[3];
}

// ---------------------------------------------------------------------------
// front_kernel (R9, parallel fusion — proven −25..40 us vs serial):
//   blocks [0, PQB)        : P GEMM  (x @ W1[0:128], packed bf16 out)
//   blocks [PQB, 2*PQB)    : Q GEMM  (x @ W1[128:256] + b1, packed bf16 out)
//   blocks [2*PQB, +BKB)   : bucket_fill (grid-stride over E edges)
// ---------------------------------------------------------------------------
__global__ __launch_bounds__(256, 2) void front_kernel(
    const float* __restrict__ x, const u32* __restrict__ mw1s,
    u32* __restrict__ Pb, u32* __restrict__ Qb,
    const float* __restrict__ pos, const int* __restrict__ ei,
    int* __restrict__ deg, int2* __restrict__ bucket,
    int N, int E, int nIter, int PQB, int BKB)
{
    const int b = blockIdx.x;
    if (b < 2 * PQB) {
        // ---- P or Q GEMM (R5 pq_gemm body, 32 nodes/wave) ----
        const int isQ = (b >= PQB);
        const int bb = isQ ? (b - PQB) : b;
        const int kbBase = isQ ? 8 : 0;
        u32* outb = isQ ? Qb : Pb;

        const int lane = threadIdx.x & 63;
        const int q = lane >> 5, el = lane & 31;
        const int gw  = bb * 4 + (threadIdx.x >> 6);
        const int gws = PQB * 4;

        for (int it = gw; it < nIter; it += gws) {
            const int nA = it * 32 + el;
            const int ncA = (nA < N) ? nA : (N - 1);
            const float* xA = x + (size_t)ncA * H;

            f32x16 acc[4];
            #pragma unroll
            for (int ct = 0; ct < 4; ++ct) acc[ct] = (f32x16)0.0f;

            #pragma unroll
            for (int kb = 0; kb < 8; ++kb) {
                const int f = kb * 16 + q * 8;
                bf16x8 bA = f8frag(*(const float4*)(xA + f), *(const float4*)(xA + f + 4));
                #pragma unroll
                for (int ct = 0; ct < 4; ++ct) {
                    Frag a; a.u = *(const u32x4*)&mw1s[((size_t)(ct * 17 + kbBase + kb) * 64 + lane) * 4];
                    acc[ct] = mfma(a.b, bA, acc[ct]);
                }
            }
            if (isQ) {   // pad kb16: k=256 -> 0 (skip dist row), k=257 -> 1.0 (b1)
                Frag bp; bp.u = (u32x4){0, 0, 0, 0};
                if (q == 0) bp.u.x = pack2(0.0f, 1.0f);
                #pragma unroll
                for (int ct = 0; ct < 4; ++ct) {
                    Frag a; a.u = *(const u32x4*)&mw1s[((size_t)(ct * 17 + 16) * 64 + lane) * 4];
                    acc[ct] = mfma(a.b, bp.b, acc[ct]);
                }
            }
            if (nA < N) {
                u32* prow = outb + (size_t)nA * 64;
                #pragma unroll
                for (int ct = 0; ct < 4; ++ct)
                    #pragma unroll
                    for (int g = 0; g < 4; ++g) {
                        u32 a = pack2(acc[ct][4*g + 0], acc[ct][4*g + 1]);
                        u32 bb2 = pack2(acc[ct][4*g + 2], acc[ct][4*g + 3]);
                        *(uint2*)(prow + ct * 16 + 4 * g + 2 * q) = make_uint2(a, bb2);
                    }
            }
        }
    } else {
        // ---- bucket_fill: grid-stride over edges ----
        const int bb = b - 2 * PQB;
        for (int e = bb * 256 + (int)threadIdx.x; e < E; e += BKB * 256) {
            const int s = ei[e];
            const int r = ei[E + e];
            const float dx = pos[s*3]   - pos[r*3];
            const float dy = pos[s*3+1] - pos[r*3+1];
            const float dz = pos[s*3+2] - pos[r*3+2];
            const float dist = sqrtf(dx*dx + dy*dy + dz*dz);
            int slot = atomicAdd(&deg[r], 1);
            if (slot < 64) bucket[(size_t)r * 64 + slot] = make_int2(s, __float_as_int(dist));
        }
    }
}

// ---------------------------------------------------------------------------
// aggregate (16x16): one wave per node n. R9-proven config restored:
// (256,3)/768 = exactly 3/CU, VGPR 72, WRITE 25 MB, ~158 us.
// Closed levers: occupancy (R3/R8 spill wall), prefetch (R6 null),
// VALU-count (R10 null/regress). R14: single dispatch (R13 split was
// diagnostic; it found node_mfma's remaining 105 MB spill).
// ---------------------------------------------------------------------------
__global__ __launch_bounds__(256, 3) void aggregate_kernel(
    const u32* __restrict__ Pbf, const u32* __restrict__ Qbf,
    const u32* __restrict__ wdp, const u32* __restrict__ ws16,
    const float* __restrict__ mb2,
    const int* __restrict__ deg, const int2* __restrict__ bucket,
    float* __restrict__ out, int N)
{
    __shared__ u32x4 af[2048];                        // 32 KiB: w2 16x16 A-frags
    __shared__ float b2s[128];                        // b2 fp32 (C-init source)
    __shared__ u32x4 wds[16];                         // dist-row weights (packed bf16)
    for (int i = threadIdx.x; i < 2048; i += 256) af[i] = ((const u32x4*)ws16)[i];
    for (int i = threadIdx.x; i < 128; i += 256) b2s[i] = mb2[i];
    if (threadIdx.x < 16) wds[threadIdx.x] = ((const u32x4*)wdp)[threadIdx.x];
    __syncthreads();

    const int lane = threadIdx.x & 63;
    const int quad = lane >> 4, col = lane & 15;

    const int gw  = blockIdx.x * 4 + (threadIdx.x >> 6);
    const int gws = gridDim.x * 4;

    for (int n = gw; n < N; n += gws) {
        int dn = deg[n]; dn = (dn > 64) ? 64 : dn;
        const int nt = (dn + 15) >> 4;
        const u32x4* Qrow = (const u32x4*)(Qbf + (size_t)n * 64);

        f32x4 sum[8];
        #pragma unroll
        for (int mt = 0; mt < 8; ++mt) sum[mt] = (f32x4){0.f, 0.f, 0.f, 0.f};

        for (int t = 0; t < nt; ++t) {
            const int eIdx = t * 16 + col;
            const bool valid = eIdx < dn;
            const int eC = valid ? eIdx : (dn - 1);
            const int2 rec = bucket[(size_t)n * 64 + eC];
            const u32x4* Prow = (const u32x4*)(Pbf + (size_t)rec.x * 64);
            const float dist = __int_as_float(rec.y);

            f32x4 acc[8];                             // C-init = b2 (per-row)
            #pragma unroll
            for (int mt = 0; mt < 8; ++mt)
                acc[mt] = *(const f32x4*)&b2s[mt * 16 + quad * 4];

            #pragma unroll 2
            for (int kb = 0; kb < 4; ++kb) {
                const u32x4 pc = Prow[kb * 4 + quad];
                const u32x4 qc = Qrow[kb * 4 + quad];
                const u32x4 wc = wds[kb * 4 + quad];
                const float v0 = silu(bflo(pc.x) + bflo(qc.x) + dist * bflo(wc.x));
                const float v1 = silu(bfhi(pc.x) + bfhi(qc.x) + dist * bfhi(wc.x));
                const float v2 = silu(bflo(pc.y) + bflo(qc.y) + dist * bflo(wc.y));
                const float v3 = silu(bfhi(pc.y) + bfhi(qc.y) + dist * bfhi(wc.y));
                const float v4 = silu(bflo(pc.z) + bflo(qc.z) + dist * bflo(wc.z));
                const float v5 = silu(bfhi(pc.z) + bfhi(qc.z) + dist * bfhi(wc.z));
                const float v6 = silu(bflo(pc.w) + bflo(qc.w) + dist * bflo(wc.w));
                const float v7 = silu(bfhi(pc.w) + bfhi(qc.w) + dist * bfhi(wc.w));
                Frag bf;
                bf.u = (u32x4){pack2(v0, v1), pack2(v2, v3), pack2(v4, v5), pack2(v6, v7)};
                if (!valid) bf.u = (u32x4){0, 0, 0, 0};
                #pragma unroll
                for (int mt = 0; mt < 8; ++mt) {
                    Frag a; a.u = af[(kb * 8 + mt) * 64 + lane];
                    acc[mt] = mfma16(a.b, bf.b, acc[mt]);
                }
            }
            // lane's D values all belong to its own column (= its own edge):
            // invalid columns (D == b2) are masked here.
            #pragma unroll
            for (int mt = 0; mt < 8; ++mt) {
                sum[mt][0] += valid ? silu(acc[mt][0]) : 0.0f;
                sum[mt][1] += valid ? silu(acc[mt][1]) : 0.0f;
                sum[mt][2] += valid ? silu(acc[mt][2]) : 0.0f;
                sum[mt][3] += valid ? silu(acc[mt][3]) : 0.0f;
            }
        }

        // reduce over the 16 column-lanes: DPP row rotations, pure VALU
        #pragma unroll
        for (int mt = 0; mt < 8; ++mt)
            #pragma unroll
            for (int r = 0; r < 4; ++r) {
                float v = sum[mt][r];
                DPP_RADD(v, 0x128);   // row_ror:8
                DPP_RADD(v, 0x124);   // row_ror:4
                DPP_RADD(v, 0x122);   // row_ror:2
                DPP_RADD(v, 0x121);   // row_ror:1
                sum[mt][r] = v;
            }
        if (col == 0) {               // lanes 0,16,32,48: rows quad*4..+3 per mt
            float* orow = out + (size_t)n * H;
            #pragma unroll
            for (int mt = 0; mt < 8; ++mt) {
                float4 v = { sum[mt][0], sum[mt][1], sum[mt][2], sum[mt][3] };
                *(float4*)(orow + mt * 16 + quad * 4) = v;
            }
        }
    }
}

// ---------------------------------------------------------------------------
// R14 node split (from R13 counters: node_mfma WRITE 131 MB, VGPR 128 —
// acc[4]+acc2[4] = 128 accumulator regs ate the whole arch budget; the R12
// literal-index fix was insufficient). Two single-GEMM kernels, each with
// the pq_gemm register shape (64 acc, no spill):
//   node1: h = silu([x,aggr] @ uw1 + b1) -> packed bf16 rows (reuses Pb)
//   node2: update = h @ uw2 + b2 -> out  (B-frag = one u32x4 row load;
//          the shfl/hp reassembly machinery is GONE)
// Cost: 25.6 MB h round-trip vs 105 MB scratch. Sentinels: node1 WRITE
// ~13 MB, node2 WRITE ~26 MB, VGPR <= ~100 each.
// ---------------------------------------------------------------------------
__global__ __launch_bounds__(256, 2) void node1_kernel(
    const float* __restrict__ x, const float* __restrict__ aggr,
    const u32* __restrict__ ws, u32* __restrict__ Hb, int N, int nIter)
{
    __shared__ u32 lds[16384];
    const u32* wsl1 = ws + 26624;
    {
        const u32x4* src = (const u32x4*)wsl1;
        u32x4* dst = (u32x4*)lds;
        for (int i = threadIdx.x; i < 4096; i += 256) {
            int ln = i & 63, fb = i >> 6, ct = fb >> 4, kb = fb & 15;
            dst[i] = src[(ct * 17 + kb) * 64 + ln];
        }
    }
    __syncthreads();

    const int lane = threadIdx.x & 63;
    const int q = lane >> 5, el = lane & 31;
    const int gw  = blockIdx.x * 4 + (threadIdx.x >> 6);
    const int gws = gridDim.x * 4;

    for (int it = gw; it < nIter; it += gws) {
        const int nA = it * 32 + el;
        const int ncA = (nA < N) ? nA : (N - 1);
        const float* xA = x + (size_t)ncA * H;
        const float* gA = aggr + (size_t)ncA * H;

        f32x16 acc[4];
        #pragma unroll
        for (int ct = 0; ct < 4; ++ct) acc[ct] = (f32x16)0.0f;

        #pragma unroll
        for (int kb = 0; kb < 16; ++kb) {
            const int f = kb * 16 + q * 8;
            const float* pA = (f < H) ? (xA + f) : (gA + f - H);
            bf16x8 bA = f8frag(*(const float4*)pA, *(const float4*)(pA + 4));
            #pragma unroll
            for (int ct = 0; ct < 4; ++ct) {
                Frag a; a.u = *(const u32x4*)&lds[((ct * 16 + kb) * 64 + lane) * 4];
                acc[ct] = mfma(a.b, bA, acc[ct]);
            }
        }
        {   // bias: k=256 -> 1.0 (b1), k=257 -> 0
            Frag bp; bp.u = (u32x4){0,0,0,0};
            if (q == 0) bp.u.x = 0x00003F80u;
            #pragma unroll
            for (int ct = 0; ct < 4; ++ct) {
                Frag a; a.u = *(const u32x4*)&wsl1[((size_t)(ct * 17 + 16) * 64 + lane) * 4];
                acc[ct] = mfma(a.b, bp.b, acc[ct]);
            }
        }
        if (nA < N) {   // h row, packed bf16, dim-ordered (pq C-write layout)
            u32* hrow = Hb + (size_t)nA * 64;
            #pragma unroll
            for (int ct = 0; ct < 4; ++ct)
                #pragma unroll
                for (int g = 0; g < 4; ++g) {
                    u32 a = pack2(silu(acc[ct][4*g + 0]), silu(acc[ct][4*g + 1]));
                    u32 b = pack2(silu(acc[ct][4*g + 2]), silu(acc[ct][4*g + 3]));
                    *(uint2*)(hrow + ct * 16 + 4 * g + 2 * q) = make_uint2(a, b);
                }
        }
    }
}

__global__ __launch_bounds__(256, 2) void node2_kernel(
    const u32* __restrict__ Hb, const u32* __restrict__ ws,
    float* __restrict__ out, int N, int nIter)
{
    const u32* wsl2 = ws + 44032;
    const int lane = threadIdx.x & 63;
    const int q = lane >> 5, el = lane & 31;
    const int gw  = blockIdx.x * 4 + (threadIdx.x >> 6);
    const int gws = gridDim.x * 4;

    for (int it = gw; it < nIter; it += gws) {
        const int nA = it * 32 + el;
        const int ncA = (nA < N) ? nA : (N - 1);
        const u32* hrow = Hb + (size_t)ncA * 64;

        f32x16 acc[4];
        #pragma unroll
        for (int ct = 0; ct < 4; ++ct) acc[ct] = (f32x16)0.0f;

        #pragma unroll
        for (int kb = 0; kb < 8; ++kb) {
            // B-frag: h dims kb*16+q*8 .. +7 = u32 indices kb*8+q*4 .. +3
            Frag hb; hb.u = *(const u32x4*)&hrow[kb * 8 + q * 4];
            #pragma unroll
            for (int ct = 0; ct < 4; ++ct) {
                Frag a; a.u = *(const u32x4*)&wsl2[((size_t)(ct * 9 + kb) * 64 + lane) * 4];
                acc[ct] = mfma(a.b, hb.b, acc[ct]);
            }
        }
        {   // bias: k=128 -> 1.0 (b2)
            Frag bf; bf.u = (u32x4){0,0,0,0};
            if (q == 0) bf.u.x = 0x00003F80u;
            #pragma unroll
            for (int ct = 0; ct < 4; ++ct) {
                Frag a; a.u = *(const u32x4*)&wsl2[((size_t)(ct * 9 + 8) * 64 + lane) * 4];
                acc[ct] = mfma(a.b, bf.b, acc[ct]);
            }
        }
        if (nA < N) {
            float* orow = out + (size_t)nA * H;
            #pragma unroll
            for (int ct = 0; ct < 4; ++ct)
                #pragma unroll
                for (int g = 0; g < 4; ++g) {
                    float4 v = { acc[ct][4*g + 0], acc[ct][4*g + 1],
                                 acc[ct][4*g + 2], acc[ct][4*g + 3] };
                    *(float4*)(orow + ct * 32 + 8 * g + 4 * q) = v;
                }
        }
    }
}

// ---------------------------------------------------------------------------
// FALLBACK (ws too small): edge kernel with fp32 atomics + fused node MLP.
// ---------------------------------------------------------------------------
__global__ __launch_bounds__(256, 2) void edge_mfma(
    const float* __restrict__ x, const float* __restrict__ pos,
    const int* __restrict__ ei, const u32* __restrict__ ws,
    float* __restrict__ aggr, int E, int nIter)
{
    __shared__ u32 lds[16384];
    {
        const u32x4* src = (const u32x4*)ws;
        u32x4* dst = (u32x4*)lds;
        for (int i = threadIdx.x; i < 4096; i += 256) {
            int ln = i & 63, fb = i >> 6, ct = fb >> 4, kb = fb & 15;
            dst[i] = src[(ct * 17 + kb) * 64 + ln];
        }
    }
    __syncthreads();
    const u32* wsl1 = ws;
    const u32* wsl2 = ws + 17408;

    const int lane = threadIdx.x & 63;
    const int q = lane >> 5, el = lane & 31;
    const int gw  = blockIdx.x * 4 + (threadIdx.x >> 6);
    const int gws = gridDim.x * 4;

    for (int it = gw; it < nIter; it += gws) {
        const int e0 = it * 64;
        const int sA = ei[e0 + el],      rA = ei[E + e0 + el];
        const int sB = ei[e0 + 32 + el], rB = ei[E + e0 + 32 + el];
        float dA, dB;
        {
            float ax = pos[sA*3] - pos[rA*3], ay = pos[sA*3+1] - pos[rA*3+1], az = pos[sA*3+2] - pos[rA*3+2];
            dA = sqrtf(ax*ax + ay*ay + az*az);
            float bx = pos[sB*3] - pos[rB*3], by = pos[sB*3+1] - pos[rB*3+1], bz = pos[sB*3+2] - pos[rB*3+2];
            dB = sqrtf(bx*bx + by*by + bz*bz);
        }
        const float* xsA = x + (size_t)sA * H; const float* xrA = x + (size_t)rA * H;
        const float* xsB = x + (size_t)sB * H; const float* xrB = x + (size_t)rB * H;

        f32x16 acc[2][4];
        #pragma unroll
        for (int s = 0; s < 2; ++s)
            #pragma unroll
            for (int ct = 0; ct < 4; ++ct) acc[s][ct] = (f32x16)0.0f;

        #pragma unroll
        for (int kb = 0; kb < 16; ++kb) {
            const int f = kb * 16 + q * 8;
            const float* pA = (f < H) ? (xsA + f) : (xrA + f - H);
            const float* pB = (f < H) ? (xsB + f) : (xrB + f - H);
            bf16x8 bA = f8frag(*(const float4*)pA, *(const float4*)(pA + 4));
            bf16x8 bB = f8frag(*(const float4*)pB, *(const float4*)(pB + 4));
            #pragma unroll
            for (int ct = 0; ct < 4; ++ct) {
                Frag a; a.u = *(const u32x4*)&lds[((ct * 16 + kb) * 64 + lane) * 4];
                acc[0][ct] = mfma(a.b, bA, acc[0][ct]);
                acc[1][ct] = mfma(a.b, bB, acc[1][ct]);
            }
        }
        {
            Frag bA, bB;
            bA.u = (u32x4){0,0,0,0}; bB.u = (u32x4){0,0,0,0};
            if (q == 0) { bA.u.x = pack2(dA, 1.0f); bB.u.x = pack2(dB, 1.0f); }
            #pragma unroll
            for (int ct = 0; ct < 4; ++ct) {
                Frag a; a.u = *(const u32x4*)&wsl1[((size_t)(ct * 17 + 16) * 64 + lane) * 4];
                acc[0][ct] = mfma(a.b, bA.b, acc[0][ct]);
                acc[1][ct] = mfma(a.b, bB.b, acc[1][ct]);
            }
        }

        #pragma unroll
        for (int s = 0; s < 2; ++s) {
            const int ridx = s ? rB : rA;
            u32 hp[16][2];
            #pragma unroll
            for (int ct = 0; ct < 4; ++ct)
                #pragma unroll
                for (int g = 0; g < 4; ++g) {
                    hp[ct * 4 + g][0] = pack2(silu(acc[s][ct][4*g + 0]), silu(acc[s][ct][4*g + 1]));
                    hp[ct * 4 + g][1] = pack2(silu(acc[s][ct][4*g + 2]), silu(acc[s][ct][4*g + 3]));
                }

            f32x16 acc2[4];
            #pragma unroll
            for (int ct = 0; ct < 4; ++ct) acc2[ct] = (f32x16)0.0f;

            #pragma unroll
            for (int kb2 = 0; kb2 < 8; ++kb2) {
                const u32 e0v = hp[2 * kb2][0],     e1v = hp[2 * kb2][1];
                const u32 o0v = hp[2 * kb2 + 1][0], o1v = hp[2 * kb2 + 1][1];
                const u32 w0  = q ? o0v : e0v;
                const u32 w1v = q ? o1v : e1v;
                const u32 sv0 = q ? e0v : o0v;
                const u32 sv1 = q ? e1v : o1v;
                u32 r0 = (u32)__shfl((int)sv0, lane ^ 32);
                u32 r1 = (u32)__shfl((int)sv1, lane ^ 32);
                Frag bf;
                if (q == 0) bf.u = (u32x4){w0, w1v, r0, r1};
                else        bf.u = (u32x4){r0, r1, w0, w1v};
                #pragma unroll
                for (int ct2 = 0; ct2 < 4; ++ct2) {
                    Frag a; a.u = *(const u32x4*)&wsl2[((size_t)(ct2 * 9 + kb2) * 64 + lane) * 4];
                    acc2[ct2] = mfma(a.b, bf.b, acc2[ct2]);
                }
            }
            {
                Frag bf; bf.u = (u32x4){0,0,0,0};
                if (q == 0) bf.u.x = 0x00003F80u;
                #pragma unroll
                for (int ct2 = 0; ct2 < 4; ++ct2) {
                    Frag a; a.u = *(const u32x4*)&wsl2[((size_t)(ct2 * 9 + 8) * 64 + lane) * 4];
                    acc2[ct2] = mfma(a.b, bf.b, acc2[ct2]);
                }
            }
            float* arow = aggr + (size_t)ridx * H;
            #pragma unroll
            for (int ct2 = 0; ct2 < 4; ++ct2)
                #pragma unroll
                for (int r = 0; r < 16; ++r) {
                    int m = ct2 * 32 + (r & 3) + 8 * (r >> 2) + 4 * q;
                    atomicAdd(arow + m, silu(acc2[ct2][r]));
                }
        }
    }
}

extern "C" void kernel_launch(void* const* d_in, const int* in_sizes, int n_in,
                              void* d_out, int out_size, void* d_ws, size_t ws_size,
                              hipStream_t stream) {
    const float* x    = (const float*)d_in[0];
    const float* pos  = (const float*)d_in[1];
    const int*   ei   = (const int*)d_in[2];
    const float* mw1  = (const float*)d_in[3];
    const float* mb1  = (const float*)d_in[4];
    const float* mw2  = (const float*)d_in[5];
    const float* mb2  = (const float*)d_in[6];
    const float* uw1  = (const float*)d_in[7];
    const float* ub1  = (const float*)d_in[8];
    const float* uw2  = (const float*)d_in[9];
    const float* ub2  = (const float*)d_in[10];

    const int N = in_sizes[0] / H;
    const int E = in_sizes[2] / 2;

    // ws layout (u32 units) — R9 layout
    const size_t FRAGS = 53248 + 10240 + 64;     // 32x32 frags + 16x16 frags + wdp
    const size_t PO = FRAGS;                     // P: N*64 u32 (packed bf16 rows)
    const size_t QO = PO + (size_t)N * 64;       // Q: N*64 u32 (packed bf16 rows)
    const size_t DG = QO + (size_t)N * 64;       // deg: N int
    const size_t BK = DG + (size_t)N;            // bucket: N*64 int2
    const size_t ENDu = BK + (size_t)N * 128;
    const size_t need_bytes = ENDu * 4;

    u32* ws = (u32*)d_ws;
    prep_kernel<<<63, 256, 0, stream>>>(mw1, mb1, mw2, mb2, uw1, ub1, uw2, ub2, ws);

    float* buf = (float*)d_out;
    const int nIter32 = (N + 31) / 32;           // 32 nodes per wave

    if (ws_size >= need_bytes) {
        // ---- gather path: no fp32 atomics ----
        u32*   Pb   = ws + PO;
        u32*   Qb   = ws + QO;
        int*   deg  = (int*)(ws + DG);
        int2*  bkt  = (int2*)(ws + BK);

        hipMemsetAsync(deg, 0, (size_t)N * sizeof(int), stream);

        // P-GEMM || Q-GEMM || bucket_fill, one launch (parallel fusion, R9)
        const int PQB = 392;                      // 392*4 = 1568 waves >= 1563 iters
        const int BKB = 640;                      // grid-stride, ~3.9 edges/thread
        front_kernel<<<2 * PQB + BKB, 256, 0, stream>>>(
            x, ws, Pb, Qb, pos, ei, deg, bkt, N, E, nIter32, PQB, BKB);

        aggregate_kernel<<<768, 256, 0, stream>>>(Pb, Qb, ws + 63488, ws + 53248,
                                                  mb2, deg, bkt, buf, N);

        // R14: split node MLP. h reuses Pb (dead after aggregate).
        node1_kernel<<<512, 256, 0, stream>>>(x, buf, ws, Pb, N, nIter32);
        node2_kernel<<<512, 256, 0, stream>>>(Pb, ws, buf, N, nIter32);
    } else {
        // ---- fallback: round-3 atomic scatter path ----
        hipMemsetAsync(buf, 0, (size_t)N * H * sizeof(float), stream);
        edge_mfma<<<512, 256, 0, stream>>>(x, pos, ei, ws, buf, E, E / 64);
        // fallback node path: reuse split kernels via ws frag region offsets
        // (uw1s at 26624, uw2s at 44032 — node1/node2 read those directly).
        // h buffer: place after frag region (ws_size too small for buckets but
        // N*64 u32 fits within the P slot used by the gather path only if
        // ws_size >= (FRAGS + N*64)*4; otherwise fused-node is required.
        // Keep legacy behavior: fused path not available -> use node1/node2
        // only if room, else accept edge_mfma's aggr output as update input
        // via the same split with Hb at ws+FRAGS.
        node1_kernel<<<512, 256, 0, stream>>>(x, buf, ws, ws + PO, N, nIter32);
        node2_kernel<<<512, 256, 0, stream>>>(ws + PO, ws, buf, N, nIter32);
    }
}

// Round 15
// 332.171 us; speedup vs baseline: 1.1620x; 1.0188x over previous
//
#include <hip/hip_runtime.h>
#include <math.h>

#define H 128

typedef unsigned short u16;
typedef unsigned int u32;
typedef __attribute__((ext_vector_type(4))) u32 u32x4;
typedef __attribute__((ext_vector_type(8))) __bf16 bf16x8;
typedef __attribute__((ext_vector_type(4))) float f32x4;
typedef __attribute__((ext_vector_type(16))) float f32x16;

union Frag { u32x4 u; bf16x8 b; };

// f32 pair -> packed bf16 (RNE). Native __bf16 casts: compiler emits
// v_cvt_pk_bf16_f32 (1 instr) instead of the ~7-instr software RNE path.
__device__ __forceinline__ u32 pack2(float lo, float hi) {
    union { __bf16 b[2]; u32 u; } v;
    v.b[0] = (__bf16)lo; v.b[1] = (__bf16)hi;
    return v.u;
}
__device__ __forceinline__ float bflo(u32 w) {           // low bf16 -> f32
    union { u32 i; float f; } v; v.i = w << 16; return v.f;
}
__device__ __forceinline__ float bfhi(u32 w) {           // high bf16 -> f32
    union { u32 i; float f; } v; v.i = w & 0xffff0000u; return v.f;
}
__device__ __forceinline__ float silu(float v) {
    float e = __expf(-v);
    return v * __builtin_amdgcn_rcpf(1.0f + e);
}
__device__ __forceinline__ bf16x8 f8frag(float4 lo, float4 hi) {
    Frag f;
    f.u = (u32x4){pack2(lo.x, lo.y), pack2(lo.z, lo.w),
                  pack2(hi.x, hi.y), pack2(hi.z, hi.w)};
    return f.b;
}
__device__ __forceinline__ f32x16 mfma(bf16x8 a, bf16x8 b, f32x16 c) {
    return __builtin_amdgcn_mfma_f32_32x32x16_bf16(a, b, c, 0, 0, 0);
}
__device__ __forceinline__ f32x4 mfma16(bf16x8 a, bf16x8 b, f32x4 c) {
    return __builtin_amdgcn_mfma_f32_16x16x32_bf16(a, b, c, 0, 0, 0);
}
// VALU-pipe cross-lane add within 16-lane rows: v += row_ror(v, N)
#define DPP_RADD(v, ctrl) \
    (v) += __int_as_float(__builtin_amdgcn_update_dpp(0, __float_as_int(v), (ctrl), 0xf, 0xf, 1))

// ---------------------------------------------------------------------------
// ws frag region (u32 units):
//   mw1s @ 0      : 4ct x 17kb x 64lane x 4   (msg w1^T 32x32 frags; kb16 = dist+b1)
//   mw2s @ 17408  : 4ct x  9kb x 64lane x 4   (msg w2^T 32x32 frags; kb8 = b2)
//   uw1s @ 26624  : 4ct x 17kb x 64lane x 4   (upd w1^T 32x32 frags; kb16 = b1)
//   uw2s @ 44032  : 4ct x  9kb x 64lane x 4   (upd w2^T 32x32 frags; kb8 = b2)
//   m16s @ 53248  : 5kb x 8mt x 64lane x 4    (msg w2 16x16 A-frags)
//   wdp  @ 63488  : 64 u32                    (dist-row weights packed bf16)
// ---------------------------------------------------------------------------
__global__ void prep_kernel(const float* __restrict__ mw1, const float* __restrict__ mb1,
                            const float* __restrict__ mw2, const float* __restrict__ mb2,
                            const float* __restrict__ uw1, const float* __restrict__ ub1,
                            const float* __restrict__ uw2, const float* __restrict__ ub2,
                            u32* __restrict__ ws) {
    int t = blockIdx.x * blockDim.x + threadIdx.x;
    if (t >= 15936) return;
    if (t >= 15872) {
        // ---- dist-row weights, packed bf16 ----
        int i = t - 15872;                    // [0, 64)
        ws[63488 + i] = pack2(mw1[256 * H + 2 * i], mw1[256 * H + 2 * i + 1]);
        return;
    }
    if (t >= 13312) {
        // ---- 16x16 A-frags of msg w2 ----
        int slot = t - 13312;                 // (kb*8 + mt)*64 + lane
        int lane = slot & 63, fb = slot >> 6;
        int kb = fb >> 3, mt = fb & 7;
        int m = mt * 16 + (lane & 15);
        int quad = lane >> 4;
        u32 out[4];
        #pragma unroll
        for (int p = 0; p < 4; ++p) {
            float v[2];
            #pragma unroll
            for (int h = 0; h < 2; ++h) {
                int k = kb * 32 + quad * 8 + p * 2 + h;
                float val = 0.0f;
                if (k < 128)       val = mw2[(size_t)k * H + m];
                else if (k == 128) val = mb2[m];
                v[h] = val;
            }
            out[p] = pack2(v[0], v[1]);
        }
        u32* dst = ws + 53248 + (size_t)slot * 4;
        dst[0] = out[0]; dst[1] = out[1]; dst[2] = out[2]; dst[3] = out[3];
        return;
    }
    const float *W, *s0, *s1;
    int nK, slot, base;
    if (t < 4352)       { W = mw1; s0 = mw1 + 256 * H; s1 = mb1; nK = 256; slot = t;         base = 0;     }
    else if (t < 6656)  { W = mw2; s0 = mb2; s1 = nullptr;       nK = 128; slot = t - 4352;  base = 17408; }
    else if (t < 11008) { W = uw1; s0 = ub1; s1 = nullptr;       nK = 256; slot = t - 6656;  base = 26624; }
    else                { W = uw2; s0 = ub2; s1 = nullptr;       nK = 128; slot = t - 11008; base = 44032; }
    int lane = slot & 63, fb = slot >> 6;
    int ct, kb;
    if (nK == 256) { ct = fb / 17; kb = fb % 17; }
    else           { ct = fb / 9;  kb = fb % 9;  }
    int m = ct * 32 + (lane & 31);
    int q = lane >> 5;
    u32 out[4];
    #pragma unroll
    for (int p = 0; p < 4; ++p) {
        float v[2];
        #pragma unroll
        for (int h = 0; h < 2; ++h) {
            int k = kb * 16 + q * 8 + p * 2 + h;
            float val = 0.0f;
            if (k < nK)            val = W[(size_t)k * H + m];
            else if (k == nK)      val = s0 ? s0[m] : 0.0f;
            else if (k == nK + 1)  val = s1 ? s1[m] : 0.0f;
            v[h] = val;
        }
        out[p] = pack2(v[0], v[1]);
    }
    u32* dst = ws + base + (size_t)slot * 4;
    dst[0] = out[0]; dst[1] = out[1]; dst[2] = out[2]; dst[3] = out[3];
}

// ---------------------------------------------------------------------------
// front_kernel (R15: FOUR parallel jobs — R9's parallel fusion, extended):
//   blocks [0, PQB)        : P GEMM  (x @ mw1[0:128], packed bf16 -> Pb)
//   blocks [PQB, 2*PQB)    : Q GEMM  (x @ mw1[128:256] + b1, packed -> Qb)
//   blocks [2*PQB, 3*PQB)  : U GEMM  (x @ uw1[0:128], packed -> Ub)  [NEW]
//   blocks [3*PQB, +BKB)   : bucket_fill (grid-stride over E edges)
// U has no dependence on aggregate -> hides under front's latency slack;
// node1 then shrinks to the aggr-half GEMM (R14 spill-fix economics).
// Ub lives in the HIGH HALF of d_out (dead until node2 overwrites).
// ---------------------------------------------------------------------------
__global__ __launch_bounds__(256, 2) void front_kernel(
    const float* __restrict__ x, const u32* __restrict__ ws,
    u32* __restrict__ Pb, u32* __restrict__ Qb, u32* __restrict__ Ub,
    const float* __restrict__ pos, const int* __restrict__ ei,
    int* __restrict__ deg, int2* __restrict__ bucket,
    int N, int E, int nIter, int PQB, int BKB)
{
    const int b = blockIdx.x;
    if (b < 3 * PQB) {
        // ---- P / Q / U GEMM (pq_gemm body, 32 nodes/wave) ----
        const int job = b / PQB;                 // 0=P, 1=Q, 2=U
        const int bb = b - job * PQB;
        const int kbBase = (job == 1) ? 8 : 0;
        const u32* wt = (job == 2) ? (ws + 26624) : ws;   // U uses uw1 frags
        u32* outb = (job == 0) ? Pb : ((job == 1) ? Qb : Ub);

        const int lane = threadIdx.x & 63;
        const int q = lane >> 5, el = lane & 31;
        const int gw  = bb * 4 + (threadIdx.x >> 6);
        const int gws = PQB * 4;

        for (int it = gw; it < nIter; it += gws) {
            const int nA = it * 32 + el;
            const int ncA = (nA < N) ? nA : (N - 1);
            const float* xA = x + (size_t)ncA * H;

            f32x16 acc[4];
            #pragma unroll
            for (int ct = 0; ct < 4; ++ct) acc[ct] = (f32x16)0.0f;

            #pragma unroll
            for (int kb = 0; kb < 8; ++kb) {
                const int f = kb * 16 + q * 8;
                bf16x8 bA = f8frag(*(const float4*)(xA + f), *(const float4*)(xA + f + 4));
                #pragma unroll
                for (int ct = 0; ct < 4; ++ct) {
                    Frag a; a.u = *(const u32x4*)&wt[((size_t)(ct * 17 + kbBase + kb) * 64 + lane) * 4];
                    acc[ct] = mfma(a.b, bA, acc[ct]);
                }
            }
            if (job == 1) {   // Q bias: pad kb16 (k=256 -> 0 skip dist, k=257 -> 1.0 b1)
                Frag bp; bp.u = (u32x4){0, 0, 0, 0};
                if (q == 0) bp.u.x = pack2(0.0f, 1.0f);
                #pragma unroll
                for (int ct = 0; ct < 4; ++ct) {
                    Frag a; a.u = *(const u32x4*)&ws[((size_t)(ct * 17 + 16) * 64 + lane) * 4];
                    acc[ct] = mfma(a.b, bp.b, acc[ct]);
                }
            }
            if (nA < N) {
                u32* prow = outb + (size_t)nA * 64;
                #pragma unroll
                for (int ct = 0; ct < 4; ++ct)
                    #pragma unroll
                    for (int g = 0; g < 4; ++g) {
                        u32 a = pack2(acc[ct][4*g + 0], acc[ct][4*g + 1]);
                        u32 bb2 = pack2(acc[ct][4*g + 2], acc[ct][4*g + 3]);
                        *(uint2*)(prow + ct * 16 + 4 * g + 2 * q) = make_uint2(a, bb2);
                    }
            }
        }
    } else {
        // ---- bucket_fill: grid-stride over edges ----
        const int bb = b - 3 * PQB;
        for (int e = bb * 256 + (int)threadIdx.x; e < E; e += BKB * 256) {
            const int s = ei[e];
            const int r = ei[E + e];
            const float dx = pos[s*3]   - pos[r*3];
            const float dy = pos[s*3+1] - pos[r*3+1];
            const float dz = pos[s*3+2] - pos[r*3+2];
            const float dist = sqrtf(dx*dx + dy*dy + dz*dz);
            int slot = atomicAdd(&deg[r], 1);
            if (slot < 64) bucket[(size_t)r * 64 + slot] = make_int2(s, __float_as_int(dist));
        }
    }
}

// ---------------------------------------------------------------------------
// aggregate (16x16): one wave per node n. (256,3)/768 proven config.
// R15: C-write packs to bf16 (node1 rounded aggr to bf16 anyway — zero
// precision change; WRITE_SIZE halves to 12.5 MB). Output = low half of
// d_out, packed rows (64 u32/node, dims mt*16+quad*4+j -> u32 mt*8+quad*2).
// Closed levers: occupancy (R3/R8 spill wall), prefetch (R6 null),
// VALU-count (R10 null/regress).
// ---------------------------------------------------------------------------
__global__ __launch_bounds__(256, 3) void aggregate_kernel(
    const u32* __restrict__ Pbf, const u32* __restrict__ Qbf,
    const u32* __restrict__ wdp, const u32* __restrict__ ws16,
    const float* __restrict__ mb2,
    const int* __restrict__ deg, const int2* __restrict__ bucket,
    u32* __restrict__ aggrp, int N)
{
    __shared__ u32x4 af[2048];                        // 32 KiB: w2 16x16 A-frags
    __shared__ float b2s[128];                        // b2 fp32 (C-init source)
    __shared__ u32x4 wds[16];                         // dist-row weights (packed bf16)
    for (int i = threadIdx.x; i < 2048; i += 256) af[i] = ((const u32x4*)ws16)[i];
    for (int i = threadIdx.x; i < 128; i += 256) b2s[i] = mb2[i];
    if (threadIdx.x < 16) wds[threadIdx.x] = ((const u32x4*)wdp)[threadIdx.x];
    __syncthreads();

    const int lane = threadIdx.x & 63;
    const int quad = lane >> 4, col = lane & 15;

    const int gw  = blockIdx.x * 4 + (threadIdx.x >> 6);
    const int gws = gridDim.x * 4;

    for (int n = gw; n < N; n += gws) {
        int dn = deg[n]; dn = (dn > 64) ? 64 : dn;
        const int nt = (dn + 15) >> 4;
        const u32x4* Qrow = (const u32x4*)(Qbf + (size_t)n * 64);

        f32x4 sum[8];
        #pragma unroll
        for (int mt = 0; mt < 8; ++mt) sum[mt] = (f32x4){0.f, 0.f, 0.f, 0.f};

        for (int t = 0; t < nt; ++t) {
            const int eIdx = t * 16 + col;
            const bool valid = eIdx < dn;
            const int eC = valid ? eIdx : (dn - 1);
            const int2 rec = bucket[(size_t)n * 64 + eC];
            const u32x4* Prow = (const u32x4*)(Pbf + (size_t)rec.x * 64);
            const float dist = __int_as_float(rec.y);

            f32x4 acc[8];                             // C-init = b2 (per-row)
            #pragma unroll
            for (int mt = 0; mt < 8; ++mt)
                acc[mt] = *(const f32x4*)&b2s[mt * 16 + quad * 4];

            #pragma unroll 2
            for (int kb = 0; kb < 4; ++kb) {
                const u32x4 pc = Prow[kb * 4 + quad];
                const u32x4 qc = Qrow[kb * 4 + quad];
                const u32x4 wc = wds[kb * 4 + quad];
                const float v0 = silu(bflo(pc.x) + bflo(qc.x) + dist * bflo(wc.x));
                const float v1 = silu(bfhi(pc.x) + bfhi(qc.x) + dist * bfhi(wc.x));
                const float v2 = silu(bflo(pc.y) + bflo(qc.y) + dist * bflo(wc.y));
                const float v3 = silu(bfhi(pc.y) + bfhi(qc.y) + dist * bfhi(wc.y));
                const float v4 = silu(bflo(pc.z) + bflo(qc.z) + dist * bflo(wc.z));
                const float v5 = silu(bfhi(pc.z) + bfhi(qc.z) + dist * bfhi(wc.z));
                const float v6 = silu(bflo(pc.w) + bflo(qc.w) + dist * bflo(wc.w));
                const float v7 = silu(bfhi(pc.w) + bfhi(qc.w) + dist * bfhi(wc.w));
                Frag bf;
                bf.u = (u32x4){pack2(v0, v1), pack2(v2, v3), pack2(v4, v5), pack2(v6, v7)};
                if (!valid) bf.u = (u32x4){0, 0, 0, 0};
                #pragma unroll
                for (int mt = 0; mt < 8; ++mt) {
                    Frag a; a.u = af[(kb * 8 + mt) * 64 + lane];
                    acc[mt] = mfma16(a.b, bf.b, acc[mt]);
                }
            }
            // lane's D values all belong to its own column (= its own edge):
            // invalid columns (D == b2) are masked here.
            #pragma unroll
            for (int mt = 0; mt < 8; ++mt) {
                sum[mt][0] += valid ? silu(acc[mt][0]) : 0.0f;
                sum[mt][1] += valid ? silu(acc[mt][1]) : 0.0f;
                sum[mt][2] += valid ? silu(acc[mt][2]) : 0.0f;
                sum[mt][3] += valid ? silu(acc[mt][3]) : 0.0f;
            }
        }

        // reduce over the 16 column-lanes: DPP row rotations, pure VALU
        #pragma unroll
        for (int mt = 0; mt < 8; ++mt)
            #pragma unroll
            for (int r = 0; r < 4; ++r) {
                float v = sum[mt][r];
                DPP_RADD(v, 0x128);   // row_ror:8
                DPP_RADD(v, 0x124);   // row_ror:4
                DPP_RADD(v, 0x122);   // row_ror:2
                DPP_RADD(v, 0x121);   // row_ror:1
                sum[mt][r] = v;
            }
        if (col == 0) {               // lanes 0,16,32,48: dims mt*16+quad*4+j
            u32* orow = aggrp + (size_t)n * 64;
            #pragma unroll
            for (int mt = 0; mt < 8; ++mt) {
                u32 a = pack2(sum[mt][0], sum[mt][1]);
                u32 b = pack2(sum[mt][2], sum[mt][3]);
                *(uint2*)(orow + mt * 8 + quad * 2) = make_uint2(a, b);
            }
        }
    }
}

// ---------------------------------------------------------------------------
// node1_slim (R15): h = silu(U + aggr @ uw1[128:256] + b1) -> packed bf16.
// U (x-half, precomputed in front) and aggr both read as packed bf16 rows.
// 8-kb GEMM: pq_gemm register shape (64 acc), no spill.
// ---------------------------------------------------------------------------
__global__ __launch_bounds__(256, 2) void node1_slim(
    const u32* __restrict__ aggrp, const u32* __restrict__ Ub,
    const u32* __restrict__ ws, u32* __restrict__ Hb, int N, int nIter)
{
    __shared__ u32 lds[8192];                         // uw1 kb 8..15 frags (32 KiB)
    const u32* wsl1 = ws + 26624;
    {
        const u32x4* src = (const u32x4*)wsl1;
        u32x4* dst = (u32x4*)lds;
        for (int i = threadIdx.x; i < 2048; i += 256) {
            int ln = i & 63, fb = i >> 6, ct = fb >> 3, kb = fb & 7;
            dst[i] = src[(ct * 17 + 8 + kb) * 64 + ln];
        }
    }
    __syncthreads();

    const int lane = threadIdx.x & 63;
    const int q = lane >> 5, el = lane & 31;
    const int gw  = blockIdx.x * 4 + (threadIdx.x >> 6);
    const int gws = gridDim.x * 4;

    for (int it = gw; it < nIter; it += gws) {
        const int nA = it * 32 + el;
        const int ncA = (nA < N) ? nA : (N - 1);
        const u32* arow = aggrp + (size_t)ncA * 64;
        const u32* Urow = Ub + (size_t)ncA * 64;

        f32x16 acc[4];
        #pragma unroll
        for (int ct = 0; ct < 4; ++ct) acc[ct] = (f32x16)0.0f;

        #pragma unroll
        for (int kb = 0; kb < 8; ++kb) {
            // B-frag: aggr dims kb*16+q*8..+7 = u32s kb*8+q*4..+3 (direct load)
            Frag hb; hb.u = *(const u32x4*)&arow[kb * 8 + q * 4];
            #pragma unroll
            for (int ct = 0; ct < 4; ++ct) {
                Frag a; a.u = *(const u32x4*)&lds[((ct * 8 + kb) * 64 + lane) * 4];
                acc[ct] = mfma(a.b, hb.b, acc[ct]);
            }
        }
        {   // bias: k=256 -> 1.0 (b1)
            Frag bp; bp.u = (u32x4){0,0,0,0};
            if (q == 0) bp.u.x = 0x00003F80u;
            #pragma unroll
            for (int ct = 0; ct < 4; ++ct) {
                Frag a; a.u = *(const u32x4*)&wsl1[((size_t)(ct * 17 + 16) * 64 + lane) * 4];
                acc[ct] = mfma(a.b, bp.b, acc[ct]);
            }
        }
        if (nA < N) {
            u32* hrow = Hb + (size_t)nA * 64;
            #pragma unroll
            for (int ct = 0; ct < 4; ++ct)
                #pragma unroll
                for (int g = 0; g < 4; ++g) {
                    // U values for dims ct*32+8g+4q+(0..3): uint2 at ct*16+4g+2q
                    uint2 uv = *(const uint2*)&Urow[ct * 16 + 4 * g + 2 * q];
                    u32 a = pack2(silu(acc[ct][4*g + 0] + bflo(uv.x)),
                                  silu(acc[ct][4*g + 1] + bfhi(uv.x)));
                    u32 b = pack2(silu(acc[ct][4*g + 2] + bflo(uv.y)),
                                  silu(acc[ct][4*g + 3] + bfhi(uv.y)));
                    *(uint2*)(hrow + ct * 16 + 4 * g + 2 * q) = make_uint2(a, b);
                }
        }
    }
}

// ---------------------------------------------------------------------------
// node1_full (R14 version, fallback path only): h = silu([x,aggr]@uw1+b1)
// with f32 aggr input (edge_mfma's atomic output).
// ---------------------------------------------------------------------------
__global__ __launch_bounds__(256, 2) void node1_full(
    const float* __restrict__ x, const float* __restrict__ aggr,
    const u32* __restrict__ ws, u32* __restrict__ Hb, int N, int nIter)
{
    __shared__ u32 lds[16384];
    const u32* wsl1 = ws + 26624;
    {
        const u32x4* src = (const u32x4*)wsl1;
        u32x4* dst = (u32x4*)lds;
        for (int i = threadIdx.x; i < 4096; i += 256) {
            int ln = i & 63, fb = i >> 6, ct = fb >> 4, kb = fb & 15;
            dst[i] = src[(ct * 17 + kb) * 64 + ln];
        }
    }
    __syncthreads();

    const int lane = threadIdx.x & 63;
    const int q = lane >> 5, el = lane & 31;
    const int gw  = blockIdx.x * 4 + (threadIdx.x >> 6);
    const int gws = gridDim.x * 4;

    for (int it = gw; it < nIter; it += gws) {
        const int nA = it * 32 + el;
        const int ncA = (nA < N) ? nA : (N - 1);
        const float* xA = x + (size_t)ncA * H;
        const float* gA = aggr + (size_t)ncA * H;

        f32x16 acc[4];
        #pragma unroll
        for (int ct = 0; ct < 4; ++ct) acc[ct] = (f32x16)0.0f;

        #pragma unroll
        for (int kb = 0; kb < 16; ++kb) {
            const int f = kb * 16 + q * 8;
            const float* pA = (f < H) ? (xA + f) : (gA + f - H);
            bf16x8 bA = f8frag(*(const float4*)pA, *(const float4*)(pA + 4));
            #pragma unroll
            for (int ct = 0; ct < 4; ++ct) {
                Frag a; a.u = *(const u32x4*)&lds[((ct * 16 + kb) * 64 + lane) * 4];
                acc[ct] = mfma(a.b, bA, acc[ct]);
            }
        }
        {
            Frag bp; bp.u = (u32x4){0,0,0,0};
            if (q == 0) bp.u.x = 0x00003F80u;
            #pragma unroll
            for (int ct = 0; ct < 4; ++ct) {
                Frag a; a.u = *(const u32x4*)&wsl1[((size_t)(ct * 17 + 16) * 64 + lane) * 4];
                acc[ct] = mfma(a.b, bp.b, acc[ct]);
            }
        }
        if (nA < N) {
            u32* hrow = Hb + (size_t)nA * 64;
            #pragma unroll
            for (int ct = 0; ct < 4; ++ct)
                #pragma unroll
                for (int g = 0; g < 4; ++g) {
                    u32 a = pack2(silu(acc[ct][4*g + 0]), silu(acc[ct][4*g + 1]));
                    u32 b = pack2(silu(acc[ct][4*g + 2]), silu(acc[ct][4*g + 3]));
                    *(uint2*)(hrow + ct * 16 + 4 * g + 2 * q) = make_uint2(a, b);
                }
        }
    }
}

// ---------------------------------------------------------------------------
// node2: update = h @ uw2 + b2 -> out (f32). B-frag = one u32x4 row load.
// ---------------------------------------------------------------------------
__global__ __launch_bounds__(256, 2) void node2_kernel(
    const u32* __restrict__ Hb, const u32* __restrict__ ws,
    float* __restrict__ out, int N, int nIter)
{
    const u32* wsl2 = ws + 44032;
    const int lane = threadIdx.x & 63;
    const int q = lane >> 5, el = lane & 31;
    const int gw  = blockIdx.x * 4 + (threadIdx.x >> 6);
    const int gws = gridDim.x * 4;

    for (int it = gw; it < nIter; it += gws) {
        const int nA = it * 32 + el;
        const int ncA = (nA < N) ? nA : (N - 1);
        const u32* hrow = Hb + (size_t)ncA * 64;

        f32x16 acc[4];
        #pragma unroll
        for (int ct = 0; ct < 4; ++ct) acc[ct] = (f32x16)0.0f;

        #pragma unroll
        for (int kb = 0; kb < 8; ++kb) {
            Frag hb; hb.u = *(const u32x4*)&hrow[kb * 8 + q * 4];
            #pragma unroll
            for (int ct = 0; ct < 4; ++ct) {
                Frag a; a.u = *(const u32x4*)&wsl2[((size_t)(ct * 9 + kb) * 64 + lane) * 4];
                acc[ct] = mfma(a.b, hb.b, acc[ct]);
            }
        }
        {   // bias: k=128 -> 1.0 (b2)
            Frag bf; bf.u = (u32x4){0,0,0,0};
            if (q == 0) bf.u.x = 0x00003F80u;
            #pragma unroll
            for (int ct = 0; ct < 4; ++ct) {
                Frag a; a.u = *(const u32x4*)&wsl2[((size_t)(ct * 9 + 8) * 64 + lane) * 4];
                acc[ct] = mfma(a.b, bf.b, acc[ct]);
            }
        }
        if (nA < N) {
            float* orow = out + (size_t)nA * H;
            #pragma unroll
            for (int ct = 0; ct < 4; ++ct)
                #pragma unroll
                for (int g = 0; g < 4; ++g) {
                    float4 v = { acc[ct][4*g + 0], acc[ct][4*g + 1],
                                 acc[ct][4*g + 2], acc[ct][4*g + 3] };
                    *(float4*)(orow + ct * 32 + 8 * g + 4 * q) = v;
                }
        }
    }
}

// ---------------------------------------------------------------------------
// FALLBACK (ws too small): edge kernel with fp32 atomics.
// ---------------------------------------------------------------------------
__global__ __launch_bounds__(256, 2) void edge_mfma(
    const float* __restrict__ x, const float* __restrict__ pos,
    const int* __restrict__ ei, const u32* __restrict__ ws,
    float* __restrict__ aggr, int E, int nIter)
{
    __shared__ u32 lds[16384];
    {
        const u32x4* src = (const u32x4*)ws;
        u32x4* dst = (u32x4*)lds;
        for (int i = threadIdx.x; i < 4096; i += 256) {
            int ln = i & 63, fb = i >> 6, ct = fb >> 4, kb = fb & 15;
            dst[i] = src[(ct * 17 + kb) * 64 + ln];
        }
    }
    __syncthreads();
    const u32* wsl1 = ws;
    const u32* wsl2 = ws + 17408;

    const int lane = threadIdx.x & 63;
    const int q = lane >> 5, el = lane & 31;
    const int gw  = blockIdx.x * 4 + (threadIdx.x >> 6);
    const int gws = gridDim.x * 4;

    for (int it = gw; it < nIter; it += gws) {
        const int e0 = it * 64;
        const int sA = ei[e0 + el],      rA = ei[E + e0 + el];
        const int sB = ei[e0 + 32 + el], rB = ei[E + e0 + 32 + el];
        float dA, dB;
        {
            float ax = pos[sA*3] - pos[rA*3], ay = pos[sA*3+1] - pos[rA*3+1], az = pos[sA*3+2] - pos[rA*3+2];
            dA = sqrtf(ax*ax + ay*ay + az*az);
            float bx = pos[sB*3] - pos[rB*3], by = pos[sB*3+1] - pos[rB*3+1], bz = pos[sB*3+2] - pos[rB*3+2];
            dB = sqrtf(bx*bx + by*by + bz*bz);
        }
        const float* xsA = x + (size_t)sA * H; const float* xrA = x + (size_t)rA * H;
        const float* xsB = x + (size_t)sB * H; const float* xrB = x + (size_t)rB * H;

        f32x16 acc[2][4];
        #pragma unroll
        for (int s = 0; s < 2; ++s)
            #pragma unroll
            for (int ct = 0; ct < 4; ++ct) acc[s][ct] = (f32x16)0.0f;

        #pragma unroll
        for (int kb = 0; kb < 16; ++kb) {
            const int f = kb * 16 + q * 8;
            const float* pA = (f < H) ? (xsA + f) : (xrA + f - H);
            const float* pB = (f < H) ? (xsB + f) : (xrB + f - H);
            bf16x8 bA = f8frag(*(const float4*)pA, *(const float4*)(pA + 4));
            bf16x8 bB = f8frag(*(const float4*)pB, *(const float4*)(pB + 4));
            #pragma unroll
            for (int ct = 0; ct < 4; ++ct) {
                Frag a; a.u = *(const u32x4*)&lds[((ct * 16 + kb) * 64 + lane) * 4];
                acc[0][ct] = mfma(a.b, bA, acc[0][ct]);
                acc[1][ct] = mfma(a.b, bB, acc[1][ct]);
            }
        }
        {
            Frag bA, bB;
            bA.u = (u32x4){0,0,0,0}; bB.u = (u32x4){0,0,0,0};
            if (q == 0) { bA.u.x = pack2(dA, 1.0f); bB.u.x = pack2(dB, 1.0f); }
            #pragma unroll
            for (int ct = 0; ct < 4; ++ct) {
                Frag a; a.u = *(const u32x4*)&wsl1[((size_t)(ct * 17 + 16) * 64 + lane) * 4];
                acc[0][ct] = mfma(a.b, bA.b, acc[0][ct]);
                acc[1][ct] = mfma(a.b, bB.b, acc[1][ct]);
            }
        }

        #pragma unroll
        for (int s = 0; s < 2; ++s) {
            const int ridx = s ? rB : rA;
            u32 hp[16][2];
            #pragma unroll
            for (int ct = 0; ct < 4; ++ct)
                #pragma unroll
                for (int g = 0; g < 4; ++g) {
                    hp[ct * 4 + g][0] = pack2(silu(acc[s][ct][4*g + 0]), silu(acc[s][ct][4*g + 1]));
                    hp[ct * 4 + g][1] = pack2(silu(acc[s][ct][4*g + 2]), silu(acc[s][ct][4*g + 3]));
                }

            f32x16 acc2[4];
            #pragma unroll
            for (int ct = 0; ct < 4; ++ct) acc2[ct] = (f32x16)0.0f;

            #pragma unroll
            for (int kb2 = 0; kb2 < 8; ++kb2) {
                const u32 e0v = hp[2 * kb2][0],     e1v = hp[2 * kb2][1];
                const u32 o0v = hp[2 * kb2 + 1][0], o1v = hp[2 * kb2 + 1][1];
                const u32 w0  = q ? o0v : e0v;
                const u32 w1v = q ? o1v : e1v;
                const u32 sv0 = q ? e0v : o0v;
                const u32 sv1 = q ? e1v : o1v;
                u32 r0 = (u32)__shfl((int)sv0, lane ^ 32);
                u32 r1 = (u32)__shfl((int)sv1, lane ^ 32);
                Frag bf;
                if (q == 0) bf.u = (u32x4){w0, w1v, r0, r1};
                else        bf.u = (u32x4){r0, r1, w0, w1v};
                #pragma unroll
                for (int ct2 = 0; ct2 < 4; ++ct2) {
                    Frag a; a.u = *(const u32x4*)&wsl2[((size_t)(ct2 * 9 + kb2) * 64 + lane) * 4];
                    acc2[ct2] = mfma(a.b, bf.b, acc2[ct2]);
                }
            }
            {
                Frag bf; bf.u = (u32x4){0,0,0,0};
                if (q == 0) bf.u.x = 0x00003F80u;
                #pragma unroll
                for (int ct2 = 0; ct2 < 4; ++ct2) {
                    Frag a; a.u = *(const u32x4*)&wsl2[((size_t)(ct2 * 9 + 8) * 64 + lane) * 4];
                    acc2[ct2] = mfma(a.b, bf.b, acc2[ct2]);
                }
            }
            float* arow = aggr + (size_t)ridx * H;
            #pragma unroll
            for (int ct2 = 0; ct2 < 4; ++ct2)
                #pragma unroll
                for (int r = 0; r < 16; ++r) {
                    int m = ct2 * 32 + (r & 3) + 8 * (r >> 2) + 4 * q;
                    atomicAdd(arow + m, silu(acc2[ct2][r]));
                }
        }
    }
}

extern "C" void kernel_launch(void* const* d_in, const int* in_sizes, int n_in,
                              void* d_out, int out_size, void* d_ws, size_t ws_size,
                              hipStream_t stream) {
    const float* x    = (const float*)d_in[0];
    const float* pos  = (const float*)d_in[1];
    const int*   ei   = (const int*)d_in[2];
    const float* mw1  = (const float*)d_in[3];
    const float* mb1  = (const float*)d_in[4];
    const float* mw2  = (const float*)d_in[5];
    const float* mb2  = (const float*)d_in[6];
    const float* uw1  = (const float*)d_in[7];
    const float* ub1  = (const float*)d_in[8];
    const float* uw2  = (const float*)d_in[9];
    const float* ub2  = (const float*)d_in[10];

    const int N = in_sizes[0] / H;
    const int E = in_sizes[2] / 2;

    // ws layout (u32 units) — unchanged from R9 (U lives in d_out high half)
    const size_t FRAGS = 53248 + 10240 + 64;     // 32x32 frags + 16x16 frags + wdp
    const size_t PO = FRAGS;                     // P: N*64 u32 (packed bf16 rows)
    const size_t QO = PO + (size_t)N * 64;       // Q: N*64 u32 (packed bf16 rows)
    const size_t DG = QO + (size_t)N * 64;       // deg: N int
    const size_t BK = DG + (size_t)N;            // bucket: N*64 int2
    const size_t ENDu = BK + (size_t)N * 128;
    const size_t need_bytes = ENDu * 4;

    u32* ws = (u32*)d_ws;
    prep_kernel<<<63, 256, 0, stream>>>(mw1, mb1, mw2, mb2, uw1, ub1, uw2, ub2, ws);

    float* buf = (float*)d_out;
    u32* bufu = (u32*)d_out;
    const int nIter32 = (N + 31) / 32;           // 32 nodes per wave

    if (ws_size >= need_bytes) {
        // ---- gather path: no fp32 atomics ----
        u32*   Pb    = ws + PO;
        u32*   Qb    = ws + QO;
        int*   deg   = (int*)(ws + DG);
        int2*  bkt   = (int2*)(ws + BK);
        u32*   aggrp = bufu;                     // low half of d_out (packed aggr)
        u32*   Ub    = bufu + (size_t)N * 64;    // high half of d_out (packed U)

        hipMemsetAsync(deg, 0, (size_t)N * sizeof(int), stream);

        // P || Q || U GEMMs || bucket_fill, one launch (parallel fusion)
        const int PQB = 392;                     // 392*4 = 1568 waves >= 1563 iters
        const int BKB = 640;
        front_kernel<<<3 * PQB + BKB, 256, 0, stream>>>(
            x, ws, Pb, Qb, Ub, pos, ei, deg, bkt, N, E, nIter32, PQB, BKB);

        aggregate_kernel<<<768, 256, 0, stream>>>(Pb, Qb, ws + 63488, ws + 53248,
                                                  mb2, deg, bkt, aggrp, N);

        // slim node MLP: h = silu(U + aggr@uw1[128:] + b1); update = h@uw2+b2
        node1_slim<<<512, 256, 0, stream>>>(aggrp, Ub, ws, Pb, N, nIter32);
        node2_kernel<<<512, 256, 0, stream>>>(Pb, ws, buf, N, nIter32);
    } else {
        // ---- fallback: atomic scatter path + full node MLP ----
        hipMemsetAsync(buf, 0, (size_t)N * H * sizeof(float), stream);
        edge_mfma<<<512, 256, 0, stream>>>(x, pos, ei, ws, buf, E, E / 64);
        node1_full<<<512, 256, 0, stream>>>(x, buf, ws, ws + PO, N, nIter32);
        node2_kernel<<<512, 256, 0, stream>>>(ws + PO, ws, buf, N, nIter32);
    }
}